// Round 3
// baseline (232.442 us; speedup 1.0000x reference)
//
#include <hip/hip_runtime.h>
#include <math.h>

typedef __attribute__((ext_vector_type(8))) short bf16x8;
typedef __attribute__((ext_vector_type(4))) float f32x4;

static constexpr int D_MODEL = 1024;
static constexpr int SEQ = 2048;
static constexpr int BATCH = 2;
static constexpr int M_TOT = BATCH * SEQ;   // 4096

__device__ __forceinline__ unsigned short f2bf(float f) {
  unsigned int u = __builtin_bit_cast(unsigned int, f);
  u += 0x7fffu + ((u >> 16) & 1u);   // round-to-nearest-even
  return (unsigned short)(u >> 16);
}

// async global -> LDS, 16B per lane.  dst must be wave-uniform base (HW: base + lane*16).
__device__ __forceinline__ void gld16(const unsigned short* g, unsigned short* l) {
  __builtin_amdgcn_global_load_lds(
      (const __attribute__((address_space(1))) unsigned int*)g,
      (__attribute__((address_space(3))) unsigned int*)l, 16, 0, 0);
}

// ---------------- prep: fp32 -> bf16 (vectorized) ----------------
__global__ void cvt_f32_bf16(const float* __restrict__ src,
                             unsigned short* __restrict__ dst, int n4) {
  int i = blockIdx.x * blockDim.x + threadIdx.x;
  if (i >= n4) return;
  const float4 v = reinterpret_cast<const float4*>(src)[i];
  ushort4 o;
  o.x = f2bf(v.x); o.y = f2bf(v.y); o.z = f2bf(v.z); o.w = f2bf(v.w);
  reinterpret_cast<ushort4*>(dst)[i] = o;
}

// ---------------- prep: RoPE cos/sin tables [SEQ][32] ----------------
__global__ void rope_tables(float* __restrict__ ctab, float* __restrict__ stab) {
  int idx = blockIdx.x * blockDim.x + threadIdx.x;
  int s = idx >> 5;
  int p = idx & 31;
  float inv_freq = powf(10000.0f, -(float)p / 32.0f);
  float ang = (float)s * inv_freq;
  ctab[idx] = cosf(ang);
  stab[idx] = sinf(ang);
}

// ---------------- GEMM (m97 structure): C[M][N] = A @ W^T ----------------
// A [M][1024] bf16 row-major, W [N][1024] bf16 row-major.  BK=32, gload_lds staging.
// MODE 0: merged QKV (N=3072): type = col>>10 -> Q/K (rope) or V (transposed store)
// MODE 2: final projection -> fp32 row-major
template <int BM, int BN, int MODE>
__global__ __launch_bounds__(256, 2)
void gemm2(const unsigned short* __restrict__ A,
           const unsigned short* __restrict__ W,
           unsigned short* __restrict__ Qd,
           unsigned short* __restrict__ Kd,
           unsigned short* __restrict__ Vd,
           float* __restrict__ Fd,
           const float* __restrict__ ctab,
           const float* __restrict__ stab) {
  constexpr int MI = BM / 32, NI = BN / 32;
  __shared__ __align__(16) unsigned short As[BM * 32];
  __shared__ __align__(16) unsigned short Bs[BN * 32];
  const int tid  = threadIdx.x;
  const int lane = tid & 63;
  const int wave = tid >> 6;
  const int wm = wave >> 1, wn = wave & 1;
  const int m0 = blockIdx.y * BM;
  const int n0 = blockIdx.x * BN;
  const int lr = lane & 15, lg = lane >> 4;

  f32x4 acc[MI][NI] = {};

  for (int kt = 0; kt < D_MODEL / 32; ++kt) {
    const int k0 = kt * 32;
#pragma unroll
    for (int rr = 0; rr < BM / 64; ++rr) {
      const int flat = (rr * 256 + tid) * 8;
      const int row = flat >> 5, col = flat & 31;
      gld16(&A[(size_t)(m0 + row) * D_MODEL + k0 + col], &As[(rr * 4 + wave) * 512]);
    }
#pragma unroll
    for (int rr = 0; rr < BN / 64; ++rr) {
      const int flat = (rr * 256 + tid) * 8;
      const int row = flat >> 5, col = flat & 31;
      gld16(&W[(size_t)(n0 + row) * D_MODEL + k0 + col], &Bs[(rr * 4 + wave) * 512]);
    }
    __syncthreads();
    bf16x8 af[MI], bfr[NI];
#pragma unroll
    for (int i = 0; i < MI; ++i)
      af[i] = *reinterpret_cast<const bf16x8*>(&As[(wm * (BM / 2) + i * 16 + lr) * 32 + lg * 8]);
#pragma unroll
    for (int j = 0; j < NI; ++j)
      bfr[j] = *reinterpret_cast<const bf16x8*>(&Bs[(wn * (BN / 2) + j * 16 + lr) * 32 + lg * 8]);
#pragma unroll
    for (int i = 0; i < MI; ++i)
#pragma unroll
      for (int j = 0; j < NI; ++j)
        acc[i][j] = __builtin_amdgcn_mfma_f32_16x16x32_bf16(af[i], bfr[j], acc[i][j], 0, 0, 0);
    __syncthreads();
  }

  // epilogue.  C/D: col = lane&15, row = (lane>>4)*4 + reg
#pragma unroll
  for (int i = 0; i < MI; ++i) {
#pragma unroll
    for (int j = 0; j < NI; ++j) {
#pragma unroll
      for (int r = 0; r < 4; ++r) {
        float x = acc[i][j][r];
        const int gm = m0 + wm * (BM / 2) + i * 16 + lg * 4 + r;
        const int gc = n0 + wn * (BN / 2) + j * 16 + lr;
        if constexpr (MODE == 2) {
          Fd[(size_t)gm * D_MODEL + gc] = x;
        } else {
          const int b = gm >> 11, s = gm & 2047;
          const int t = gc >> 10, c = gc & 1023;
          const int n = c >> 6, h = c & 63;
          if (t < 2) {  // Q or K: fused RoPE
            const float co = ctab[s * 32 + (h >> 1)];
            const float sn = stab[s * 32 + (h >> 1)];
            const float part = __shfl_xor(x, 1, 64);
            x = (h & 1) ? (part * sn + x * co) : (x * co - part * sn);
            unsigned short* dst = (t == 0) ? Qd : Kd;
            dst[(size_t)((b * 16 + n) * SEQ + s) * 64 + h] = f2bf(x);
          } else {      // V transposed [bn][h][s]
            Vd[(size_t)((b * 16 + n) * 64 + h) * SEQ + s] = f2bf(x);
          }
        }
      }
    }
  }
}

// ---------------- flash attention v3, causal ----------------
// 16 q-rows per wave -> 4096 waves (4/SIMD).  Unnormalized exp (bounded scores),
// deferred row-sum.  KVBLK=64.  V loaded after P stored (reg time-share with K).
// grid: (32 bn, 32 qt reversed heavy-first).  4 independent waves/block.
__global__ __launch_bounds__(256, 3)
void attn_kernel(const unsigned short* __restrict__ Q,
                 const unsigned short* __restrict__ K,
                 const unsigned short* __restrict__ Vt,
                 unsigned short* __restrict__ AO) {
  __shared__ unsigned short Pl[4][16 * 72];
  const int bn   = blockIdx.x;
  const int qt   = (gridDim.y - 1) - blockIdx.y;
  const int wave = threadIdx.x >> 6;
  const int lane = threadIdx.x & 63;
  const int lr = lane & 15, lg = lane >> 4;
  const int q0 = qt * 64 + wave * 16;
  const unsigned short* Qh = Q  + (size_t)bn * SEQ * 64;
  const unsigned short* Kh = K  + (size_t)bn * SEQ * 64;
  const unsigned short* Vh = Vt + (size_t)bn * 64 * SEQ;
  unsigned short* Pw = &Pl[wave][0];

  bf16x8 qf[2];
#pragma unroll
  for (int ks = 0; ks < 2; ++ks)
    qf[ks] = *reinterpret_cast<const bf16x8*>(&Qh[(size_t)(q0 + lr) * 64 + ks * 32 + lg * 8]);

  f32x4 o[4] = {};
  float lsum[4] = {};
  constexpr float KL2E = 0.125f * 1.44269504088896f;

  const int nkt = (q0 + 16 + 63) >> 6;
  for (int kt = 0; kt < nkt; ++kt) {
    const int k0 = kt * 64;
    // ---- K loads + QK^T ----
    bf16x8 kf[4][2];
#pragma unroll
    for (int nj = 0; nj < 4; ++nj)
#pragma unroll
      for (int ks = 0; ks < 2; ++ks)
        kf[nj][ks] = *reinterpret_cast<const bf16x8*>(
            &Kh[(size_t)(k0 + nj * 16 + lr) * 64 + ks * 32 + lg * 8]);
    f32x4 sf[4] = {};
#pragma unroll
    for (int nj = 0; nj < 4; ++nj)
#pragma unroll
      for (int ks = 0; ks < 2; ++ks)
        sf[nj] = __builtin_amdgcn_mfma_f32_16x16x32_bf16(qf[ks], kf[nj][ks], sf[nj], 0, 0, 0);

    // ---- p = exp2(s*KL2E); mask only on boundary tiles; P -> LDS ----
    if (k0 + 63 <= q0) {      // fully unmasked tile (wave-uniform)
#pragma unroll
      for (int nj = 0; nj < 4; ++nj)
#pragma unroll
        for (int r = 0; r < 4; ++r) {
          const float p = exp2f(sf[nj][r] * KL2E);
          lsum[r] += p;
          Pw[(lg * 4 + r) * 72 + nj * 16 + lr] = f2bf(p);
        }
    } else {
#pragma unroll
      for (int nj = 0; nj < 4; ++nj)
#pragma unroll
        for (int r = 0; r < 4; ++r) {
          const int qrow = q0 + lg * 4 + r;
          const int kcol = k0 + nj * 16 + lr;
          const float p = (kcol <= qrow) ? exp2f(sf[nj][r] * KL2E) : 0.0f;
          lsum[r] += p;
          Pw[(lg * 4 + r) * 72 + nj * 16 + lr] = f2bf(p);
        }
    }

    // ---- V loads issued under the LDS roundtrip (K regs dead now) ----
    bf16x8 vf[2][4];
#pragma unroll
    for (int ks2 = 0; ks2 < 2; ++ks2)
#pragma unroll
      for (int hf = 0; hf < 4; ++hf)
        vf[ks2][hf] = *reinterpret_cast<const bf16x8*>(
            &Vh[(size_t)(hf * 16 + lr) * SEQ + k0 + ks2 * 32 + lg * 8]);

    asm volatile("s_waitcnt lgkmcnt(0)" ::: "memory");
    bf16x8 pf[2];
#pragma unroll
    for (int ks2 = 0; ks2 < 2; ++ks2)
      pf[ks2] = *reinterpret_cast<const bf16x8*>(&Pw[lr * 72 + ks2 * 32 + lg * 8]);

    // ---- O += P @ V ----
#pragma unroll
    for (int ks2 = 0; ks2 < 2; ++ks2)
#pragma unroll
      for (int hf = 0; hf < 4; ++hf)
        o[hf] = __builtin_amdgcn_mfma_f32_16x16x32_bf16(pf[ks2], vf[ks2][hf], o[hf], 0, 0, 0);
  }

  // ---- deferred row-sum reduce + normalize + store ----
  const int b = bn >> 4, n = bn & 15;
#pragma unroll
  for (int r = 0; r < 4; ++r) {
    float s = lsum[r];
#pragma unroll
    for (int d = 1; d < 16; d <<= 1) s += __shfl_xor(s, d, 64);
    const float inv = 1.0f / s;
    const int srow = q0 + lg * 4 + r;
#pragma unroll
    for (int hf = 0; hf < 4; ++hf) {
      const int h = hf * 16 + lr;
      AO[(size_t)(b * SEQ + srow) * D_MODEL + n * 64 + h] = f2bf(o[hf][r] * inv);
    }
  }
}

// ---------------- launch ----------------
extern "C" void kernel_launch(void* const* d_in, const int* in_sizes, int n_in,
                              void* d_out, int out_size, void* d_ws, size_t ws_size,
                              hipStream_t stream) {
  const float* qw = (const float*)d_in[0];
  const float* kw = (const float*)d_in[1];
  const float* vw = (const float*)d_in[2];
  const float* ow = (const float*)d_in[3];
  const float* x  = (const float*)d_in[4];

  char* ws = (char*)d_ws;
  const size_t XB = (size_t)M_TOT * D_MODEL * 2;      // 8 MB
  const size_t WB = (size_t)D_MODEL * D_MODEL * 2;    // 2 MB
  unsigned short* Xb  = (unsigned short*)ws;  ws += XB;
  unsigned short* Wqb = (unsigned short*)ws;  ws += WB;  // Wq|Wk|Wv contiguous -> [3072][1024]
  unsigned short* Wkb = (unsigned short*)ws;  ws += WB;
  unsigned short* Wvb = (unsigned short*)ws;  ws += WB;
  unsigned short* Wob = (unsigned short*)ws;  ws += WB;
  unsigned short* Qr  = (unsigned short*)ws;  ws += XB;
  unsigned short* Kr  = (unsigned short*)ws;  ws += XB;
  unsigned short* Vt  = (unsigned short*)ws;  ws += XB;
  unsigned short* AO  = (unsigned short*)ws;  ws += XB;
  float* ctab = (float*)ws;  ws += (size_t)SEQ * 32 * 4;
  float* stab = (float*)ws;  ws += (size_t)SEQ * 32 * 4;

  cvt_f32_bf16<<<(M_TOT * D_MODEL / 4) / 256, 256, 0, stream>>>(x, Xb, M_TOT * D_MODEL / 4);
  cvt_f32_bf16<<<(D_MODEL * D_MODEL / 4) / 256, 256, 0, stream>>>(qw, Wqb, D_MODEL * D_MODEL / 4);
  cvt_f32_bf16<<<(D_MODEL * D_MODEL / 4) / 256, 256, 0, stream>>>(kw, Wkb, D_MODEL * D_MODEL / 4);
  cvt_f32_bf16<<<(D_MODEL * D_MODEL / 4) / 256, 256, 0, stream>>>(vw, Wvb, D_MODEL * D_MODEL / 4);
  cvt_f32_bf16<<<(D_MODEL * D_MODEL / 4) / 256, 256, 0, stream>>>(ow, Wob, D_MODEL * D_MODEL / 4);
  rope_tables<<<(SEQ * 32) / 256, 256, 0, stream>>>(ctab, stab);

  // merged QKV projection: N = 3072
  gemm2<128, 128, 0><<<dim3(3072 / 128, M_TOT / 128), 256, 0, stream>>>(
      Xb, Wqb, Qr, Kr, Vt, nullptr, ctab, stab);

  attn_kernel<<<dim3(BATCH * 16, SEQ / 64), 256, 0, stream>>>(Qr, Kr, Vt, AO);

  // final projection: N = 1024, 128x64 tile -> 512 blocks
  gemm2<128, 64, 2><<<dim3(D_MODEL / 64, M_TOT / 128), 256, 0, stream>>>(
      AO, Wob, nullptr, nullptr, nullptr, (float*)d_out, nullptr, nullptr);
}

// Round 4
// 198.919 us; speedup vs baseline: 1.1685x; 1.1685x over previous
//
#include <hip/hip_runtime.h>
#include <math.h>

typedef __attribute__((ext_vector_type(8))) short bf16x8;
typedef __attribute__((ext_vector_type(4))) float f32x4;

static constexpr int D_MODEL = 1024;
static constexpr int SEQ = 2048;
static constexpr int BATCH = 2;
static constexpr int M_TOT = BATCH * SEQ;   // 4096

__device__ __forceinline__ unsigned short f2bf(float f) {
  unsigned int u = __builtin_bit_cast(unsigned int, f);
  u += 0x7fffu + ((u >> 16) & 1u);   // round-to-nearest-even
  return (unsigned short)(u >> 16);
}

// async global -> LDS, 16B per lane.  dst must be wave-uniform base (HW: base + lane*16).
__device__ __forceinline__ void gld16(const unsigned short* g, unsigned short* l) {
  __builtin_amdgcn_global_load_lds(
      (const __attribute__((address_space(1))) unsigned int*)g,
      (__attribute__((address_space(3))) unsigned int*)l, 16, 0, 0);
}

// ---------------- prep: fp32 -> bf16 (vectorized) ----------------
__global__ void cvt_f32_bf16(const float* __restrict__ src,
                             unsigned short* __restrict__ dst, int n4) {
  int i = blockIdx.x * blockDim.x + threadIdx.x;
  if (i >= n4) return;
  const float4 v = reinterpret_cast<const float4*>(src)[i];
  ushort4 o;
  o.x = f2bf(v.x); o.y = f2bf(v.y); o.z = f2bf(v.z); o.w = f2bf(v.w);
  reinterpret_cast<ushort4*>(dst)[i] = o;
}

// ---------------- prep: RoPE cos/sin tables [SEQ][32] ----------------
__global__ void rope_tables(float* __restrict__ ctab, float* __restrict__ stab) {
  int idx = blockIdx.x * blockDim.x + threadIdx.x;
  int s = idx >> 5;
  int p = idx & 31;
  float inv_freq = powf(10000.0f, -(float)p / 32.0f);
  float ang = (float)s * inv_freq;
  ctab[idx] = cosf(ang);
  stab[idx] = sinf(ang);
}

// ---------------- GEMM (m97 structure): C[M][N] = A @ W^T ----------------
// (unchanged from round 3 — keep bisectable)
template <int BM, int BN, int MODE>
__global__ __launch_bounds__(256, 2)
void gemm2(const unsigned short* __restrict__ A,
           const unsigned short* __restrict__ W,
           unsigned short* __restrict__ Qd,
           unsigned short* __restrict__ Kd,
           unsigned short* __restrict__ Vd,
           float* __restrict__ Fd,
           const float* __restrict__ ctab,
           const float* __restrict__ stab) {
  constexpr int MI = BM / 32, NI = BN / 32;
  __shared__ __align__(16) unsigned short As[BM * 32];
  __shared__ __align__(16) unsigned short Bs[BN * 32];
  const int tid  = threadIdx.x;
  const int lane = tid & 63;
  const int wave = tid >> 6;
  const int wm = wave >> 1, wn = wave & 1;
  const int m0 = blockIdx.y * BM;
  const int n0 = blockIdx.x * BN;
  const int lr = lane & 15, lg = lane >> 4;

  f32x4 acc[MI][NI] = {};

  for (int kt = 0; kt < D_MODEL / 32; ++kt) {
    const int k0 = kt * 32;
#pragma unroll
    for (int rr = 0; rr < BM / 64; ++rr) {
      const int flat = (rr * 256 + tid) * 8;
      const int row = flat >> 5, col = flat & 31;
      gld16(&A[(size_t)(m0 + row) * D_MODEL + k0 + col], &As[(rr * 4 + wave) * 512]);
    }
#pragma unroll
    for (int rr = 0; rr < BN / 64; ++rr) {
      const int flat = (rr * 256 + tid) * 8;
      const int row = flat >> 5, col = flat & 31;
      gld16(&W[(size_t)(n0 + row) * D_MODEL + k0 + col], &Bs[(rr * 4 + wave) * 512]);
    }
    __syncthreads();
    bf16x8 af[MI], bfr[NI];
#pragma unroll
    for (int i = 0; i < MI; ++i)
      af[i] = *reinterpret_cast<const bf16x8*>(&As[(wm * (BM / 2) + i * 16 + lr) * 32 + lg * 8]);
#pragma unroll
    for (int j = 0; j < NI; ++j)
      bfr[j] = *reinterpret_cast<const bf16x8*>(&Bs[(wn * (BN / 2) + j * 16 + lr) * 32 + lg * 8]);
#pragma unroll
    for (int i = 0; i < MI; ++i)
#pragma unroll
      for (int j = 0; j < NI; ++j)
        acc[i][j] = __builtin_amdgcn_mfma_f32_16x16x32_bf16(af[i], bfr[j], acc[i][j], 0, 0, 0);
    __syncthreads();
  }

  // epilogue.  C/D: col = lane&15, row = (lane>>4)*4 + reg
#pragma unroll
  for (int i = 0; i < MI; ++i) {
#pragma unroll
    for (int j = 0; j < NI; ++j) {
#pragma unroll
      for (int r = 0; r < 4; ++r) {
        float x = acc[i][j][r];
        const int gm = m0 + wm * (BM / 2) + i * 16 + lg * 4 + r;
        const int gc = n0 + wn * (BN / 2) + j * 16 + lr;
        if constexpr (MODE == 2) {
          Fd[(size_t)gm * D_MODEL + gc] = x;
        } else {
          const int b = gm >> 11, s = gm & 2047;
          const int t = gc >> 10, c = gc & 1023;
          const int n = c >> 6, h = c & 63;
          if (t < 2) {  // Q or K: fused RoPE
            const float co = ctab[s * 32 + (h >> 1)];
            const float sn = stab[s * 32 + (h >> 1)];
            const float part = __shfl_xor(x, 1, 64);
            x = (h & 1) ? (part * sn + x * co) : (x * co - part * sn);
            unsigned short* dst = (t == 0) ? Qd : Kd;
            dst[(size_t)((b * 16 + n) * SEQ + s) * 64 + h] = f2bf(x);
          } else {      // V transposed [bn][h][s]
            Vd[(size_t)((b * 16 + n) * 64 + h) * SEQ + s] = f2bf(x);
          }
        }
      }
    }
  }
}

// ---------------- flash attention v4, causal ----------------
// Round-2 shape (32 q-rows/wave, KVBLK=64, unnormalized exp, deferred row-sum)
// + register double-buffered K/V prefetch (named A/B buffers, 2-unrolled loop —
// never runtime-indexed) + s_setprio around MFMA clusters.
// grid: (32 bn, 16 qt reversed heavy-first).  4 independent waves/block.
__global__ __launch_bounds__(256, 2)
void attn_kernel(const unsigned short* __restrict__ Q,
                 const unsigned short* __restrict__ K,
                 const unsigned short* __restrict__ Vt,
                 unsigned short* __restrict__ AO) {
  __shared__ unsigned short Pl[4][32 * 72];
  const int bn   = blockIdx.x;
  const int qt   = (gridDim.y - 1) - blockIdx.y;   // heavy-first
  const int wave = threadIdx.x >> 6;
  const int lane = threadIdx.x & 63;
  const int lr = lane & 15, lg = lane >> 4;
  const int q0 = qt * 128 + wave * 32;
  const unsigned short* Qh = Q  + (size_t)bn * SEQ * 64;
  const unsigned short* Kh = K  + (size_t)bn * SEQ * 64;
  const unsigned short* Vh = Vt + (size_t)bn * 64 * SEQ;
  unsigned short* Pw = &Pl[wave][0];

  bf16x8 qf[2][2];
#pragma unroll
  for (int mi = 0; mi < 2; ++mi)
#pragma unroll
    for (int ks = 0; ks < 2; ++ks)
      qf[mi][ks] = *reinterpret_cast<const bf16x8*>(
          &Qh[(size_t)(q0 + mi * 16 + lr) * 64 + ks * 32 + lg * 8]);

  f32x4 o[2][4] = {};
  float lsum[2][4] = {};
  constexpr float KL2E = 0.125f * 1.44269504088896f;
  const int nkt = (q0 + 32 + 63) >> 6;

  bf16x8 kfA[4][2], kfB[4][2], vfA[2][4], vfB[2][4];

  auto loadK = [&](bf16x8 (&kf)[4][2], int k0) {
#pragma unroll
    for (int nj = 0; nj < 4; ++nj)
#pragma unroll
      for (int ks = 0; ks < 2; ++ks)
        kf[nj][ks] = *reinterpret_cast<const bf16x8*>(
            &Kh[(size_t)(k0 + nj * 16 + lr) * 64 + ks * 32 + lg * 8]);
  };
  auto loadV = [&](bf16x8 (&vf)[2][4], int k0) {
#pragma unroll
    for (int ks2 = 0; ks2 < 2; ++ks2)
#pragma unroll
      for (int hf = 0; hf < 4; ++hf)
        vf[ks2][hf] = *reinterpret_cast<const bf16x8*>(
            &Vh[(size_t)(hf * 16 + lr) * SEQ + k0 + ks2 * 32 + lg * 8]);
  };

  auto tile = [&](bf16x8 (&kfc)[4][2], bf16x8 (&vfc)[2][4],
                  bf16x8 (&kfn)[4][2], bf16x8 (&vfn)[2][4], int kt) {
    const int k0 = kt * 64;
    const bool pre = (kt + 1 < nkt);
    // prefetch next K before consuming current (counted vmcnt: waits for kfc only)
    if (pre) loadK(kfn, k0 + 64);

    // ---- S = Q K^T ----
    f32x4 sf[2][4] = {};
    __builtin_amdgcn_s_setprio(1);
#pragma unroll
    for (int nj = 0; nj < 4; ++nj)
#pragma unroll
      for (int ks = 0; ks < 2; ++ks)
#pragma unroll
        for (int mi = 0; mi < 2; ++mi)
          sf[mi][nj] = __builtin_amdgcn_mfma_f32_16x16x32_bf16(qf[mi][ks], kfc[nj][ks], sf[mi][nj], 0, 0, 0);
    __builtin_amdgcn_s_setprio(0);

    // prefetch next V: needed 1.5 tiles from now
    if (pre) loadV(vfn, k0 + 64);

    // ---- p = exp2(s*KL2E); mask only boundary tiles; P -> LDS ----
    if (k0 + 63 <= q0) {
#pragma unroll
      for (int mi = 0; mi < 2; ++mi)
#pragma unroll
        for (int nj = 0; nj < 4; ++nj)
#pragma unroll
          for (int r = 0; r < 4; ++r) {
            const float p = exp2f(sf[mi][nj][r] * KL2E);
            lsum[mi][r] += p;
            Pw[(mi * 16 + lg * 4 + r) * 72 + nj * 16 + lr] = f2bf(p);
          }
    } else {
#pragma unroll
      for (int mi = 0; mi < 2; ++mi)
#pragma unroll
        for (int nj = 0; nj < 4; ++nj)
#pragma unroll
          for (int r = 0; r < 4; ++r) {
            const int qrow = q0 + mi * 16 + lg * 4 + r;
            const int kcol = k0 + nj * 16 + lr;
            const float p = (kcol <= qrow) ? exp2f(sf[mi][nj][r] * KL2E) : 0.0f;
            lsum[mi][r] += p;
            Pw[(mi * 16 + lg * 4 + r) * 72 + nj * 16 + lr] = f2bf(p);
          }
    }
    asm volatile("s_waitcnt lgkmcnt(0)" ::: "memory");
    bf16x8 pf[2][2];
#pragma unroll
    for (int mi = 0; mi < 2; ++mi)
#pragma unroll
      for (int ks2 = 0; ks2 < 2; ++ks2)
        pf[mi][ks2] = *reinterpret_cast<const bf16x8*>(&Pw[(mi * 16 + lr) * 72 + ks2 * 32 + lg * 8]);

    // ---- O += P @ V (vfc was issued a full tile ago — latency hidden) ----
    __builtin_amdgcn_s_setprio(1);
#pragma unroll
    for (int ks2 = 0; ks2 < 2; ++ks2)
#pragma unroll
      for (int hf = 0; hf < 4; ++hf)
#pragma unroll
        for (int mi = 0; mi < 2; ++mi)
          o[mi][hf] = __builtin_amdgcn_mfma_f32_16x16x32_bf16(pf[mi][ks2], vfc[ks2][hf], o[mi][hf], 0, 0, 0);
    __builtin_amdgcn_s_setprio(0);
  };

  loadK(kfA, 0);
  loadV(vfA, 0);
  for (int kt = 0; kt < nkt; kt += 2) {
    tile(kfA, vfA, kfB, vfB, kt);
    if (kt + 1 < nkt) tile(kfB, vfB, kfA, vfA, kt + 1);
  }

  // ---- deferred row-sum reduce + normalize + store ----
  const int b = bn >> 4, n = bn & 15;
#pragma unroll
  for (int mi = 0; mi < 2; ++mi)
#pragma unroll
    for (int r = 0; r < 4; ++r) {
      float s = lsum[mi][r];
#pragma unroll
      for (int d = 1; d < 16; d <<= 1) s += __shfl_xor(s, d, 64);
      const float inv = 1.0f / s;
      const int srow = q0 + mi * 16 + lg * 4 + r;
#pragma unroll
      for (int hf = 0; hf < 4; ++hf) {
        const int h = hf * 16 + lr;
        AO[(size_t)(b * SEQ + srow) * D_MODEL + n * 64 + h] = f2bf(o[mi][hf][r] * inv);
      }
    }
}

// ---------------- launch ----------------
extern "C" void kernel_launch(void* const* d_in, const int* in_sizes, int n_in,
                              void* d_out, int out_size, void* d_ws, size_t ws_size,
                              hipStream_t stream) {
  const float* qw = (const float*)d_in[0];
  const float* kw = (const float*)d_in[1];
  const float* vw = (const float*)d_in[2];
  const float* ow = (const float*)d_in[3];
  const float* x  = (const float*)d_in[4];

  char* ws = (char*)d_ws;
  const size_t XB = (size_t)M_TOT * D_MODEL * 2;      // 8 MB
  const size_t WB = (size_t)D_MODEL * D_MODEL * 2;    // 2 MB
  unsigned short* Xb  = (unsigned short*)ws;  ws += XB;
  unsigned short* Wqb = (unsigned short*)ws;  ws += WB;  // Wq|Wk|Wv contiguous -> [3072][1024]
  unsigned short* Wkb = (unsigned short*)ws;  ws += WB;
  unsigned short* Wvb = (unsigned short*)ws;  ws += WB;
  unsigned short* Wob = (unsigned short*)ws;  ws += WB;
  unsigned short* Qr  = (unsigned short*)ws;  ws += XB;
  unsigned short* Kr  = (unsigned short*)ws;  ws += XB;
  unsigned short* Vt  = (unsigned short*)ws;  ws += XB;
  unsigned short* AO  = (unsigned short*)ws;  ws += XB;
  float* ctab = (float*)ws;  ws += (size_t)SEQ * 32 * 4;
  float* stab = (float*)ws;  ws += (size_t)SEQ * 32 * 4;

  cvt_f32_bf16<<<(M_TOT * D_MODEL / 4) / 256, 256, 0, stream>>>(x, Xb, M_TOT * D_MODEL / 4);
  cvt_f32_bf16<<<(D_MODEL * D_MODEL / 4) / 256, 256, 0, stream>>>(qw, Wqb, D_MODEL * D_MODEL / 4);
  cvt_f32_bf16<<<(D_MODEL * D_MODEL / 4) / 256, 256, 0, stream>>>(kw, Wkb, D_MODEL * D_MODEL / 4);
  cvt_f32_bf16<<<(D_MODEL * D_MODEL / 4) / 256, 256, 0, stream>>>(vw, Wvb, D_MODEL * D_MODEL / 4);
  cvt_f32_bf16<<<(D_MODEL * D_MODEL / 4) / 256, 256, 0, stream>>>(ow, Wob, D_MODEL * D_MODEL / 4);
  rope_tables<<<(SEQ * 32) / 256, 256, 0, stream>>>(ctab, stab);

  // merged QKV projection: N = 3072
  gemm2<128, 128, 0><<<dim3(3072 / 128, M_TOT / 128), 256, 0, stream>>>(
      Xb, Wqb, Qr, Kr, Vt, nullptr, ctab, stab);

  attn_kernel<<<dim3(BATCH * 16, SEQ / 128), 256, 0, stream>>>(Qr, Kr, Vt, AO);

  // final projection: N = 1024, 128x64 tile -> 512 blocks
  gemm2<128, 64, 2><<<dim3(D_MODEL / 64, M_TOT / 128), 256, 0, stream>>>(
      AO, Wob, nullptr, nullptr, nullptr, (float*)d_out, nullptr, nullptr);
}

// Round 5
// 189.957 us; speedup vs baseline: 1.2237x; 1.0472x over previous
//
#include <hip/hip_runtime.h>
#include <math.h>

typedef __attribute__((ext_vector_type(8))) short bf16x8;
typedef __attribute__((ext_vector_type(4))) float f32x4;

static constexpr int D_MODEL = 1024;
static constexpr int SEQ = 2048;
static constexpr int BATCH = 2;
static constexpr int M_TOT = BATCH * SEQ;   // 4096

__device__ __forceinline__ unsigned short f2bf(float f) {
  unsigned int u = __builtin_bit_cast(unsigned int, f);
  u += 0x7fffu + ((u >> 16) & 1u);   // round-to-nearest-even
  return (unsigned short)(u >> 16);
}

// async global -> LDS, 16B per lane.  dst must be wave-uniform base (HW: base + lane*16).
__device__ __forceinline__ void gld16(const unsigned short* g, unsigned short* l) {
  __builtin_amdgcn_global_load_lds(
      (const __attribute__((address_space(1))) unsigned int*)g,
      (__attribute__((address_space(3))) unsigned int*)l, 16, 0, 0);
}

// ---------------- prep: fp32 -> bf16 (vectorized) ----------------
__global__ void cvt_f32_bf16(const float* __restrict__ src,
                             unsigned short* __restrict__ dst, int n4) {
  int i = blockIdx.x * blockDim.x + threadIdx.x;
  if (i >= n4) return;
  const float4 v = reinterpret_cast<const float4*>(src)[i];
  ushort4 o;
  o.x = f2bf(v.x); o.y = f2bf(v.y); o.z = f2bf(v.z); o.w = f2bf(v.w);
  reinterpret_cast<ushort4*>(dst)[i] = o;
}

// ---------------- prep: RoPE cos/sin tables [SEQ][32] ----------------
__global__ void rope_tables(float* __restrict__ ctab, float* __restrict__ stab) {
  int idx = blockIdx.x * blockDim.x + threadIdx.x;
  int s = idx >> 5;
  int p = idx & 31;
  float inv_freq = powf(10000.0f, -(float)p / 32.0f);
  float ang = (float)s * inv_freq;
  ctab[idx] = cosf(ang);
  stab[idx] = sinf(ang);
}

// ---------------- GEMM (m97 structure): C[M][N] = A @ W^T ----------------
// (unchanged — keep bisectable)
template <int BM, int BN, int MODE>
__global__ __launch_bounds__(256, 2)
void gemm2(const unsigned short* __restrict__ A,
           const unsigned short* __restrict__ W,
           unsigned short* __restrict__ Qd,
           unsigned short* __restrict__ Kd,
           unsigned short* __restrict__ Vd,
           float* __restrict__ Fd,
           const float* __restrict__ ctab,
           const float* __restrict__ stab) {
  constexpr int MI = BM / 32, NI = BN / 32;
  __shared__ __align__(16) unsigned short As[BM * 32];
  __shared__ __align__(16) unsigned short Bs[BN * 32];
  const int tid  = threadIdx.x;
  const int lane = tid & 63;
  const int wave = tid >> 6;
  const int wm = wave >> 1, wn = wave & 1;
  const int m0 = blockIdx.y * BM;
  const int n0 = blockIdx.x * BN;
  const int lr = lane & 15, lg = lane >> 4;

  f32x4 acc[MI][NI] = {};

  for (int kt = 0; kt < D_MODEL / 32; ++kt) {
    const int k0 = kt * 32;
#pragma unroll
    for (int rr = 0; rr < BM / 64; ++rr) {
      const int flat = (rr * 256 + tid) * 8;
      const int row = flat >> 5, col = flat & 31;
      gld16(&A[(size_t)(m0 + row) * D_MODEL + k0 + col], &As[(rr * 4 + wave) * 512]);
    }
#pragma unroll
    for (int rr = 0; rr < BN / 64; ++rr) {
      const int flat = (rr * 256 + tid) * 8;
      const int row = flat >> 5, col = flat & 31;
      gld16(&W[(size_t)(n0 + row) * D_MODEL + k0 + col], &Bs[(rr * 4 + wave) * 512]);
    }
    __syncthreads();
    bf16x8 af[MI], bfr[NI];
#pragma unroll
    for (int i = 0; i < MI; ++i)
      af[i] = *reinterpret_cast<const bf16x8*>(&As[(wm * (BM / 2) + i * 16 + lr) * 32 + lg * 8]);
#pragma unroll
    for (int j = 0; j < NI; ++j)
      bfr[j] = *reinterpret_cast<const bf16x8*>(&Bs[(wn * (BN / 2) + j * 16 + lr) * 32 + lg * 8]);
#pragma unroll
    for (int i = 0; i < MI; ++i)
#pragma unroll
      for (int j = 0; j < NI; ++j)
        acc[i][j] = __builtin_amdgcn_mfma_f32_16x16x32_bf16(af[i], bfr[j], acc[i][j], 0, 0, 0);
    __syncthreads();
  }

  // epilogue.  C/D: col = lane&15, row = (lane>>4)*4 + reg
#pragma unroll
  for (int i = 0; i < MI; ++i) {
#pragma unroll
    for (int j = 0; j < NI; ++j) {
#pragma unroll
      for (int r = 0; r < 4; ++r) {
        float x = acc[i][j][r];
        const int gm = m0 + wm * (BM / 2) + i * 16 + lg * 4 + r;
        const int gc = n0 + wn * (BN / 2) + j * 16 + lr;
        if constexpr (MODE == 2) {
          Fd[(size_t)gm * D_MODEL + gc] = x;
        } else {
          const int b = gm >> 11, s = gm & 2047;
          const int t = gc >> 10, c = gc & 1023;
          const int n = c >> 6, h = c & 63;
          if (t < 2) {  // Q or K: fused RoPE
            const float co = ctab[s * 32 + (h >> 1)];
            const float sn = stab[s * 32 + (h >> 1)];
            const float part = __shfl_xor(x, 1, 64);
            x = (h & 1) ? (part * sn + x * co) : (x * co - part * sn);
            unsigned short* dst = (t == 0) ? Qd : Kd;
            dst[(size_t)((b * 16 + n) * SEQ + s) * 64 + h] = f2bf(x);
          } else {      // V transposed [bn][h][s]
            Vd[(size_t)((b * 16 + n) * 64 + h) * SEQ + s] = f2bf(x);
          }
        }
      }
    }
  }
}

// ---------------- flash attention v5: complementary-pair dual-chain ----------------
// Each wave owns q-tiles qa = pj*32 (light) and qb = (63-pj)*32 (heavy):
//   - nkt(qa)+nkt(qb) = const -> perfect load balance, no tail
//   - shared K/V tile regs for the common k-prefix (kt < nkta)
//   - two independent dependence chains -> in-wave ILP
// Unnormalized exp (bounded scores), deferred row-sum.  KVBLK=64.
// grid: (32 bn, 8).  4 independent waves/block, 1024 waves total.
__global__ __launch_bounds__(256, 2)
void attn_kernel(const unsigned short* __restrict__ Q,
                 const unsigned short* __restrict__ K,
                 const unsigned short* __restrict__ Vt,
                 unsigned short* __restrict__ AO) {
  __shared__ unsigned short Pl[4][2][32 * 72];   // [wave][chain][P]
  const int bn   = blockIdx.x;
  const int wave = threadIdx.x >> 6;
  const int lane = threadIdx.x & 63;
  const int lr = lane & 15, lg = lane >> 4;
  const int pj = blockIdx.y * 4 + wave;          // 0..31
  const int qa0 = pj * 32;
  const int qb0 = (63 - pj) * 32;
  const unsigned short* Qh = Q  + (size_t)bn * SEQ * 64;
  const unsigned short* Kh = K  + (size_t)bn * SEQ * 64;
  const unsigned short* Vh = Vt + (size_t)bn * 64 * SEQ;
  unsigned short* PwA = &Pl[wave][0][0];
  unsigned short* PwB = &Pl[wave][1][0];

  bf16x8 qfA[2][2], qfB[2][2];
#pragma unroll
  for (int mi = 0; mi < 2; ++mi)
#pragma unroll
    for (int ks = 0; ks < 2; ++ks) {
      qfA[mi][ks] = *reinterpret_cast<const bf16x8*>(
          &Qh[(size_t)(qa0 + mi * 16 + lr) * 64 + ks * 32 + lg * 8]);
      qfB[mi][ks] = *reinterpret_cast<const bf16x8*>(
          &Qh[(size_t)(qb0 + mi * 16 + lr) * 64 + ks * 32 + lg * 8]);
    }

  f32x4 oA[2][4] = {}, oB[2][4] = {};
  float lsA[2][4] = {}, lsB[2][4] = {};
  constexpr float KL2E = 0.125f * 1.44269504088896f;

  const int nkta = (qa0 + 32 + 63) >> 6;
  const int nktb = (qb0 + 32 + 63) >> 6;

  for (int kt = 0; kt < nktb; ++kt) {
    const int k0 = kt * 64;
    const bool doA = (kt < nkta);

    // ---- K tile -> regs (shared by both chains) ----
    bf16x8 kf[4][2];
#pragma unroll
    for (int nj = 0; nj < 4; ++nj)
#pragma unroll
      for (int ks = 0; ks < 2; ++ks)
        kf[nj][ks] = *reinterpret_cast<const bf16x8*>(
            &Kh[(size_t)(k0 + nj * 16 + lr) * 64 + ks * 32 + lg * 8]);

    // ---- QK^T: chain B always, chain A in shared prefix ----
    f32x4 sfB[2][4] = {};
    __builtin_amdgcn_s_setprio(1);
#pragma unroll
    for (int nj = 0; nj < 4; ++nj)
#pragma unroll
      for (int ks = 0; ks < 2; ++ks)
#pragma unroll
        for (int mi = 0; mi < 2; ++mi)
          sfB[mi][nj] = __builtin_amdgcn_mfma_f32_16x16x32_bf16(qfB[mi][ks], kf[nj][ks], sfB[mi][nj], 0, 0, 0);
    __builtin_amdgcn_s_setprio(0);
    f32x4 sfA[2][4] = {};
    if (doA) {
      __builtin_amdgcn_s_setprio(1);
#pragma unroll
      for (int nj = 0; nj < 4; ++nj)
#pragma unroll
        for (int ks = 0; ks < 2; ++ks)
#pragma unroll
          for (int mi = 0; mi < 2; ++mi)
            sfA[mi][nj] = __builtin_amdgcn_mfma_f32_16x16x32_bf16(qfA[mi][ks], kf[nj][ks], sfA[mi][nj], 0, 0, 0);
      __builtin_amdgcn_s_setprio(0);
    }

    // ---- V tile -> regs (issued well before PV; kf regs can retire) ----
    bf16x8 vf[2][4];
#pragma unroll
    for (int ks2 = 0; ks2 < 2; ++ks2)
#pragma unroll
      for (int hf = 0; hf < 4; ++hf)
        vf[ks2][hf] = *reinterpret_cast<const bf16x8*>(
            &Vh[(size_t)(hf * 16 + lr) * SEQ + k0 + ks2 * 32 + lg * 8]);

    // ---- exp + mask + row-sum + P->LDS : chain B ----
    if (k0 + 63 <= qb0) {
#pragma unroll
      for (int mi = 0; mi < 2; ++mi)
#pragma unroll
        for (int nj = 0; nj < 4; ++nj)
#pragma unroll
          for (int r = 0; r < 4; ++r) {
            const float p = exp2f(sfB[mi][nj][r] * KL2E);
            lsB[mi][r] += p;
            PwB[(mi * 16 + lg * 4 + r) * 72 + nj * 16 + lr] = f2bf(p);
          }
    } else {
#pragma unroll
      for (int mi = 0; mi < 2; ++mi)
#pragma unroll
        for (int nj = 0; nj < 4; ++nj)
#pragma unroll
          for (int r = 0; r < 4; ++r) {
            const int qrow = qb0 + mi * 16 + lg * 4 + r;
            const int kcol = k0 + nj * 16 + lr;
            const float p = (kcol <= qrow) ? exp2f(sfB[mi][nj][r] * KL2E) : 0.0f;
            lsB[mi][r] += p;
            PwB[(mi * 16 + lg * 4 + r) * 72 + nj * 16 + lr] = f2bf(p);
          }
    }
    // ---- chain A ----
    if (doA) {
      if (k0 + 63 <= qa0) {
#pragma unroll
        for (int mi = 0; mi < 2; ++mi)
#pragma unroll
          for (int nj = 0; nj < 4; ++nj)
#pragma unroll
            for (int r = 0; r < 4; ++r) {
              const float p = exp2f(sfA[mi][nj][r] * KL2E);
              lsA[mi][r] += p;
              PwA[(mi * 16 + lg * 4 + r) * 72 + nj * 16 + lr] = f2bf(p);
            }
      } else {
#pragma unroll
        for (int mi = 0; mi < 2; ++mi)
#pragma unroll
          for (int nj = 0; nj < 4; ++nj)
#pragma unroll
            for (int r = 0; r < 4; ++r) {
              const int qrow = qa0 + mi * 16 + lg * 4 + r;
              const int kcol = k0 + nj * 16 + lr;
              const float p = (kcol <= qrow) ? exp2f(sfA[mi][nj][r] * KL2E) : 0.0f;
              lsA[mi][r] += p;
              PwA[(mi * 16 + lg * 4 + r) * 72 + nj * 16 + lr] = f2bf(p);
            }
      }
    }

    asm volatile("s_waitcnt lgkmcnt(0)" ::: "memory");

    // ---- PV: chain B ----
    bf16x8 pfB[2][2];
#pragma unroll
    for (int mi = 0; mi < 2; ++mi)
#pragma unroll
      for (int ks2 = 0; ks2 < 2; ++ks2)
        pfB[mi][ks2] = *reinterpret_cast<const bf16x8*>(&PwB[(mi * 16 + lr) * 72 + ks2 * 32 + lg * 8]);
    __builtin_amdgcn_s_setprio(1);
#pragma unroll
    for (int ks2 = 0; ks2 < 2; ++ks2)
#pragma unroll
      for (int hf = 0; hf < 4; ++hf)
#pragma unroll
        for (int mi = 0; mi < 2; ++mi)
          oB[mi][hf] = __builtin_amdgcn_mfma_f32_16x16x32_bf16(pfB[mi][ks2], vf[ks2][hf], oB[mi][hf], 0, 0, 0);
    __builtin_amdgcn_s_setprio(0);
    // ---- PV: chain A ----
    if (doA) {
      bf16x8 pfA[2][2];
#pragma unroll
      for (int mi = 0; mi < 2; ++mi)
#pragma unroll
        for (int ks2 = 0; ks2 < 2; ++ks2)
          pfA[mi][ks2] = *reinterpret_cast<const bf16x8*>(&PwA[(mi * 16 + lr) * 72 + ks2 * 32 + lg * 8]);
      __builtin_amdgcn_s_setprio(1);
#pragma unroll
      for (int ks2 = 0; ks2 < 2; ++ks2)
#pragma unroll
        for (int hf = 0; hf < 4; ++hf)
#pragma unroll
          for (int mi = 0; mi < 2; ++mi)
            oA[mi][hf] = __builtin_amdgcn_mfma_f32_16x16x32_bf16(pfA[mi][ks2], vf[ks2][hf], oA[mi][hf], 0, 0, 0);
      __builtin_amdgcn_s_setprio(0);
    }
  }

  // ---- deferred row-sum reduce + normalize + store, both chains ----
  const int b = bn >> 4, n = bn & 15;
#pragma unroll
  for (int mi = 0; mi < 2; ++mi)
#pragma unroll
    for (int r = 0; r < 4; ++r) {
      float sA = lsA[mi][r], sB = lsB[mi][r];
#pragma unroll
      for (int d = 1; d < 16; d <<= 1) {
        sA += __shfl_xor(sA, d, 64);
        sB += __shfl_xor(sB, d, 64);
      }
      const float invA = 1.0f / sA;
      const float invB = 1.0f / sB;
      const int ra = qa0 + mi * 16 + lg * 4 + r;
      const int rb = qb0 + mi * 16 + lg * 4 + r;
#pragma unroll
      for (int hf = 0; hf < 4; ++hf) {
        const int h = hf * 16 + lr;
        AO[(size_t)(b * SEQ + ra) * D_MODEL + n * 64 + h] = f2bf(oA[mi][hf][r] * invA);
        AO[(size_t)(b * SEQ + rb) * D_MODEL + n * 64 + h] = f2bf(oB[mi][hf][r] * invB);
      }
    }
}

// ---------------- launch ----------------
extern "C" void kernel_launch(void* const* d_in, const int* in_sizes, int n_in,
                              void* d_out, int out_size, void* d_ws, size_t ws_size,
                              hipStream_t stream) {
  const float* qw = (const float*)d_in[0];
  const float* kw = (const float*)d_in[1];
  const float* vw = (const float*)d_in[2];
  const float* ow = (const float*)d_in[3];
  const float* x  = (const float*)d_in[4];

  char* ws = (char*)d_ws;
  const size_t XB = (size_t)M_TOT * D_MODEL * 2;      // 8 MB
  const size_t WB = (size_t)D_MODEL * D_MODEL * 2;    // 2 MB
  unsigned short* Xb  = (unsigned short*)ws;  ws += XB;
  unsigned short* Wqb = (unsigned short*)ws;  ws += WB;  // Wq|Wk|Wv contiguous -> [3072][1024]
  unsigned short* Wkb = (unsigned short*)ws;  ws += WB;
  unsigned short* Wvb = (unsigned short*)ws;  ws += WB;
  unsigned short* Wob = (unsigned short*)ws;  ws += WB;
  unsigned short* Qr  = (unsigned short*)ws;  ws += XB;
  unsigned short* Kr  = (unsigned short*)ws;  ws += XB;
  unsigned short* Vt  = (unsigned short*)ws;  ws += XB;
  unsigned short* AO  = (unsigned short*)ws;  ws += XB;
  float* ctab = (float*)ws;  ws += (size_t)SEQ * 32 * 4;
  float* stab = (float*)ws;  ws += (size_t)SEQ * 32 * 4;

  cvt_f32_bf16<<<(M_TOT * D_MODEL / 4) / 256, 256, 0, stream>>>(x, Xb, M_TOT * D_MODEL / 4);
  cvt_f32_bf16<<<(D_MODEL * D_MODEL / 4) / 256, 256, 0, stream>>>(qw, Wqb, D_MODEL * D_MODEL / 4);
  cvt_f32_bf16<<<(D_MODEL * D_MODEL / 4) / 256, 256, 0, stream>>>(kw, Wkb, D_MODEL * D_MODEL / 4);
  cvt_f32_bf16<<<(D_MODEL * D_MODEL / 4) / 256, 256, 0, stream>>>(vw, Wvb, D_MODEL * D_MODEL / 4);
  cvt_f32_bf16<<<(D_MODEL * D_MODEL / 4) / 256, 256, 0, stream>>>(ow, Wob, D_MODEL * D_MODEL / 4);
  rope_tables<<<(SEQ * 32) / 256, 256, 0, stream>>>(ctab, stab);

  // merged QKV projection: N = 3072
  gemm2<128, 128, 0><<<dim3(3072 / 128, M_TOT / 128), 256, 0, stream>>>(
      Xb, Wqb, Qr, Kr, Vt, nullptr, ctab, stab);

  attn_kernel<<<dim3(BATCH * 16, 8), 256, 0, stream>>>(Qr, Kr, Vt, AO);

  // final projection: N = 1024, 128x64 tile -> 512 blocks
  gemm2<128, 64, 2><<<dim3(D_MODEL / 64, M_TOT / 128), 256, 0, stream>>>(
      AO, Wob, nullptr, nullptr, nullptr, (float*)d_out, nullptr, nullptr);
}

// Round 6
// 150.106 us; speedup vs baseline: 1.5485x; 1.2655x over previous
//
#include <hip/hip_runtime.h>
#include <math.h>

typedef __attribute__((ext_vector_type(8))) short bf16x8;
typedef __attribute__((ext_vector_type(4))) float f32x4;

static constexpr int D_MODEL = 1024;
static constexpr int SEQ = 2048;
static constexpr int BATCH = 2;
static constexpr int M_TOT = BATCH * SEQ;   // 4096

__device__ __forceinline__ unsigned short f2bf(float f) {
  unsigned int u = __builtin_bit_cast(unsigned int, f);
  u += 0x7fffu + ((u >> 16) & 1u);   // round-to-nearest-even
  return (unsigned short)(u >> 16);
}

// async global -> LDS, 16B per lane.  dst must be wave-uniform base (HW: base + lane*16).
__device__ __forceinline__ void gld16(const unsigned short* g, unsigned short* l) {
  __builtin_amdgcn_global_load_lds(
      (const __attribute__((address_space(1))) unsigned int*)g,
      (__attribute__((address_space(3))) unsigned int*)l, 16, 0, 0);
}

// ---------------- prep: fp32 -> bf16 (vectorized) ----------------
__global__ void cvt_f32_bf16(const float* __restrict__ src,
                             unsigned short* __restrict__ dst, int n4) {
  int i = blockIdx.x * blockDim.x + threadIdx.x;
  if (i >= n4) return;
  const float4 v = reinterpret_cast<const float4*>(src)[i];
  ushort4 o;
  o.x = f2bf(v.x); o.y = f2bf(v.y); o.z = f2bf(v.z); o.w = f2bf(v.w);
  reinterpret_cast<ushort4*>(dst)[i] = o;
}

// ---------------- prep: RoPE cos/sin tables [SEQ][32] ----------------
__global__ void rope_tables(float* __restrict__ ctab, float* __restrict__ stab) {
  int idx = blockIdx.x * blockDim.x + threadIdx.x;
  int s = idx >> 5;
  int p = idx & 31;
  float inv_freq = powf(10000.0f, -(float)p / 32.0f);
  float ang = (float)s * inv_freq;
  ctab[idx] = cosf(ang);
  stab[idx] = sinf(ang);
}

// ---------------- GEMM (m97 structure): C[M][N] = A @ W^T ----------------
// (unchanged — keep bisectable)
template <int BM, int BN, int MODE>
__global__ __launch_bounds__(256, 2)
void gemm2(const unsigned short* __restrict__ A,
           const unsigned short* __restrict__ W,
           unsigned short* __restrict__ Qd,
           unsigned short* __restrict__ Kd,
           unsigned short* __restrict__ Vd,
           float* __restrict__ Fd,
           const float* __restrict__ ctab,
           const float* __restrict__ stab) {
  constexpr int MI = BM / 32, NI = BN / 32;
  __shared__ __align__(16) unsigned short As[BM * 32];
  __shared__ __align__(16) unsigned short Bs[BN * 32];
  const int tid  = threadIdx.x;
  const int lane = tid & 63;
  const int wave = tid >> 6;
  const int wm = wave >> 1, wn = wave & 1;
  const int m0 = blockIdx.y * BM;
  const int n0 = blockIdx.x * BN;
  const int lr = lane & 15, lg = lane >> 4;

  f32x4 acc[MI][NI] = {};

  for (int kt = 0; kt < D_MODEL / 32; ++kt) {
    const int k0 = kt * 32;
#pragma unroll
    for (int rr = 0; rr < BM / 64; ++rr) {
      const int flat = (rr * 256 + tid) * 8;
      const int row = flat >> 5, col = flat & 31;
      gld16(&A[(size_t)(m0 + row) * D_MODEL + k0 + col], &As[(rr * 4 + wave) * 512]);
    }
#pragma unroll
    for (int rr = 0; rr < BN / 64; ++rr) {
      const int flat = (rr * 256 + tid) * 8;
      const int row = flat >> 5, col = flat & 31;
      gld16(&W[(size_t)(n0 + row) * D_MODEL + k0 + col], &Bs[(rr * 4 + wave) * 512]);
    }
    __syncthreads();
    bf16x8 af[MI], bfr[NI];
#pragma unroll
    for (int i = 0; i < MI; ++i)
      af[i] = *reinterpret_cast<const bf16x8*>(&As[(wm * (BM / 2) + i * 16 + lr) * 32 + lg * 8]);
#pragma unroll
    for (int j = 0; j < NI; ++j)
      bfr[j] = *reinterpret_cast<const bf16x8*>(&Bs[(wn * (BN / 2) + j * 16 + lr) * 32 + lg * 8]);
#pragma unroll
    for (int i = 0; i < MI; ++i)
#pragma unroll
      for (int j = 0; j < NI; ++j)
        acc[i][j] = __builtin_amdgcn_mfma_f32_16x16x32_bf16(af[i], bfr[j], acc[i][j], 0, 0, 0);
    __syncthreads();
  }

  // epilogue.  C/D: col = lane&15, row = (lane>>4)*4 + reg
#pragma unroll
  for (int i = 0; i < MI; ++i) {
#pragma unroll
    for (int j = 0; j < NI; ++j) {
#pragma unroll
      for (int r = 0; r < 4; ++r) {
        float x = acc[i][j][r];
        const int gm = m0 + wm * (BM / 2) + i * 16 + lg * 4 + r;
        const int gc = n0 + wn * (BN / 2) + j * 16 + lr;
        if constexpr (MODE == 2) {
          Fd[(size_t)gm * D_MODEL + gc] = x;
        } else {
          const int b = gm >> 11, s = gm & 2047;
          const int t = gc >> 10, c = gc & 1023;
          const int n = c >> 6, h = c & 63;
          if (t < 2) {  // Q or K: fused RoPE
            const float co = ctab[s * 32 + (h >> 1)];
            const float sn = stab[s * 32 + (h >> 1)];
            const float part = __shfl_xor(x, 1, 64);
            x = (h & 1) ? (part * sn + x * co) : (x * co - part * sn);
            unsigned short* dst = (t == 0) ? Qd : Kd;
            dst[(size_t)((b * 16 + n) * SEQ + s) * 64 + h] = f2bf(x);
          } else {      // V transposed [bn][h][s]
            Vd[(size_t)((b * 16 + n) * 64 + h) * SEQ + s] = f2bf(x);
          }
        }
      }
    }
  }
}

// ---------------- flash attention v6: block-shared LDS K/V, double-buffered ----------------
// 2 waves/block, q-block = 64 rows (wave owns 32).  K/V 64x64 tiles staged once per
// block via global_load_lds (linear LDS dst, inverse-XOR-swizzled GLOBAL src; reads
// apply the same XOR -> conflict-free ds_read_b128).  2-phase pipeline:
// stage(t+1) || compute(t); vmcnt(0); barrier.  Unnormalized exp, deferred row-sum.
// grid: (32 bn, 32 qt heavy-first).  LDS 41KB -> 3 blocks/CU.
__global__ __launch_bounds__(128, 2)
void attn_kernel(const unsigned short* __restrict__ Q,
                 const unsigned short* __restrict__ K,
                 const unsigned short* __restrict__ Vt,
                 unsigned short* __restrict__ AO) {
  __shared__ __align__(16) unsigned short Ksh[2][4096];  // [buf][64r x 64c] swizzled
  __shared__ __align__(16) unsigned short Vsh[2][4096];  // [buf][64h x 64s] swizzled
  __shared__ unsigned short Pl[2][32 * 72];              // [wave][P]
  const int bn   = blockIdx.x;
  const int j    = (gridDim.y - 1) - blockIdx.y;   // heavy-first: j=31 dispatched first
  const int wave = threadIdx.x >> 6;
  const int lane = threadIdx.x & 63;
  const int lr = lane & 15, lg = lane >> 4;
  const int q0 = j * 64 + wave * 32;
  const unsigned short* Qh = Q  + (size_t)bn * SEQ * 64;
  const unsigned short* Kh = K  + (size_t)bn * SEQ * 64;
  const unsigned short* Vh = Vt + (size_t)bn * 64 * SEQ;
  unsigned short* Pw = &Pl[wave][0];

  // staging geometry: chunk = 8 rows x 128B = 1KB, one gld16 per wave per chunk.
  // swizzle: physical col16 = logical col16 ^ (row & 7)  (involution, applied on
  // the GLOBAL source here and on every LDS read below).
  const int srow8 = lane >> 3;                         // row within chunk
  const int scol  = ((lane & 7) ^ srow8) * 8;          // swizzled source element col

  const int nt = j + 1;   // causal k-tiles of 64 for this q-block

  // ---- Q fragments in registers ----
  bf16x8 qf[2][2];
#pragma unroll
  for (int mi = 0; mi < 2; ++mi)
#pragma unroll
    for (int ks = 0; ks < 2; ++ks)
      qf[mi][ks] = *reinterpret_cast<const bf16x8*>(
          &Qh[(size_t)(q0 + mi * 16 + lr) * 64 + ks * 32 + lg * 8]);

  f32x4 o[2][4] = {};
  float lsum[2][4] = {};
  constexpr float KL2E = 0.125f * 1.44269504088896f;

  // ---- prologue: stage tile 0 into buf 0 ----
  {
#pragma unroll
    for (int c = 0; c < 4; ++c) {
      const int ch = wave * 4 + c;
      const int row = ch * 8 + srow8;
      gld16(&Kh[(size_t)row * 64 + scol], &Ksh[0][ch * 512]);
      gld16(&Vh[(size_t)row * SEQ + scol], &Vsh[0][ch * 512]);
    }
  }
  asm volatile("s_waitcnt vmcnt(0)" ::: "memory");
  __syncthreads();

  for (int t = 0; t < nt; ++t) {
    const int k0 = t * 64;
    const int cur = t & 1;

    // ---- stage tile t+1 into the other buffer (async, overlaps compute) ----
    if (t + 1 < nt) {
      const int nk0 = k0 + 64;
      const int nb = cur ^ 1;
#pragma unroll
      for (int c = 0; c < 4; ++c) {
        const int ch = wave * 4 + c;
        const int row = ch * 8 + srow8;
        gld16(&Kh[(size_t)(nk0 + row) * 64 + scol], &Ksh[nb][ch * 512]);
        gld16(&Vh[(size_t)row * SEQ + nk0 + scol], &Vsh[nb][ch * 512]);
      }
    }

    const unsigned short* Kc = &Ksh[cur][0];
    const unsigned short* Vc = &Vsh[cur][0];

    // ---- K frags from LDS (XOR-swizzled read) + QK^T ----
    bf16x8 kf[4][2];
#pragma unroll
    for (int nj = 0; nj < 4; ++nj)
#pragma unroll
      for (int ks = 0; ks < 2; ++ks) {
        const int R = nj * 16 + lr;
        const int c16 = (ks * 4 + lg) ^ (R & 7);
        kf[nj][ks] = *reinterpret_cast<const bf16x8*>(&Kc[R * 64 + c16 * 8]);
      }
    f32x4 sf[2][4] = {};
    __builtin_amdgcn_s_setprio(1);
#pragma unroll
    for (int nj = 0; nj < 4; ++nj)
#pragma unroll
      for (int ks = 0; ks < 2; ++ks)
#pragma unroll
        for (int mi = 0; mi < 2; ++mi)
          sf[mi][nj] = __builtin_amdgcn_mfma_f32_16x16x32_bf16(qf[mi][ks], kf[nj][ks], sf[mi][nj], 0, 0, 0);
    __builtin_amdgcn_s_setprio(0);

    // ---- p = exp2(s*KL2E); mask only boundary tiles; P -> LDS ----
    if (k0 + 63 <= q0) {
#pragma unroll
      for (int mi = 0; mi < 2; ++mi)
#pragma unroll
        for (int nj = 0; nj < 4; ++nj)
#pragma unroll
          for (int r = 0; r < 4; ++r) {
            const float p = exp2f(sf[mi][nj][r] * KL2E);
            lsum[mi][r] += p;
            Pw[(mi * 16 + lg * 4 + r) * 72 + nj * 16 + lr] = f2bf(p);
          }
    } else {
#pragma unroll
      for (int mi = 0; mi < 2; ++mi)
#pragma unroll
        for (int nj = 0; nj < 4; ++nj)
#pragma unroll
          for (int r = 0; r < 4; ++r) {
            const int qrow = q0 + mi * 16 + lg * 4 + r;
            const int kcol = k0 + nj * 16 + lr;
            const float p = (kcol <= qrow) ? exp2f(sf[mi][nj][r] * KL2E) : 0.0f;
            lsum[mi][r] += p;
            Pw[(mi * 16 + lg * 4 + r) * 72 + nj * 16 + lr] = f2bf(p);
          }
    }

    // ---- V frags from LDS (swizzled) ----
    bf16x8 vf[2][4];
#pragma unroll
    for (int ks2 = 0; ks2 < 2; ++ks2)
#pragma unroll
      for (int hf = 0; hf < 4; ++hf) {
        const int R = hf * 16 + lr;
        const int c16 = (ks2 * 4 + lg) ^ (R & 7);
        vf[ks2][hf] = *reinterpret_cast<const bf16x8*>(&Vc[R * 64 + c16 * 8]);
      }

    asm volatile("s_waitcnt lgkmcnt(0)" ::: "memory");
    bf16x8 pf[2][2];
#pragma unroll
    for (int mi = 0; mi < 2; ++mi)
#pragma unroll
      for (int ks2 = 0; ks2 < 2; ++ks2)
        pf[mi][ks2] = *reinterpret_cast<const bf16x8*>(&Pw[(mi * 16 + lr) * 72 + ks2 * 32 + lg * 8]);

    // ---- O += P @ V ----
    __builtin_amdgcn_s_setprio(1);
#pragma unroll
    for (int ks2 = 0; ks2 < 2; ++ks2)
#pragma unroll
      for (int hf = 0; hf < 4; ++hf)
#pragma unroll
        for (int mi = 0; mi < 2; ++mi)
          o[mi][hf] = __builtin_amdgcn_mfma_f32_16x16x32_bf16(pf[mi][ks2], vf[ks2][hf], o[mi][hf], 0, 0, 0);
    __builtin_amdgcn_s_setprio(0);

    // ---- pipeline boundary: staged loads landed, all reads of cur done ----
    asm volatile("s_waitcnt vmcnt(0)" ::: "memory");
    __syncthreads();
  }

  // ---- deferred row-sum reduce + normalize + store ----
  const int b = bn >> 4, n = bn & 15;
#pragma unroll
  for (int mi = 0; mi < 2; ++mi)
#pragma unroll
    for (int r = 0; r < 4; ++r) {
      float s = lsum[mi][r];
#pragma unroll
      for (int d = 1; d < 16; d <<= 1) s += __shfl_xor(s, d, 64);
      const float inv = 1.0f / s;
      const int srow = q0 + mi * 16 + lg * 4 + r;
#pragma unroll
      for (int hf = 0; hf < 4; ++hf) {
        const int h = hf * 16 + lr;
        AO[(size_t)(b * SEQ + srow) * D_MODEL + n * 64 + h] = f2bf(o[mi][hf][r] * inv);
      }
    }
}

// ---------------- launch ----------------
extern "C" void kernel_launch(void* const* d_in, const int* in_sizes, int n_in,
                              void* d_out, int out_size, void* d_ws, size_t ws_size,
                              hipStream_t stream) {
  const float* qw = (const float*)d_in[0];
  const float* kw = (const float*)d_in[1];
  const float* vw = (const float*)d_in[2];
  const float* ow = (const float*)d_in[3];
  const float* x  = (const float*)d_in[4];

  char* ws = (char*)d_ws;
  const size_t XB = (size_t)M_TOT * D_MODEL * 2;      // 8 MB
  const size_t WB = (size_t)D_MODEL * D_MODEL * 2;    // 2 MB
  unsigned short* Xb  = (unsigned short*)ws;  ws += XB;
  unsigned short* Wqb = (unsigned short*)ws;  ws += WB;  // Wq|Wk|Wv contiguous -> [3072][1024]
  unsigned short* Wkb = (unsigned short*)ws;  ws += WB;
  unsigned short* Wvb = (unsigned short*)ws;  ws += WB;
  unsigned short* Wob = (unsigned short*)ws;  ws += WB;
  unsigned short* Qr  = (unsigned short*)ws;  ws += XB;
  unsigned short* Kr  = (unsigned short*)ws;  ws += XB;
  unsigned short* Vt  = (unsigned short*)ws;  ws += XB;
  unsigned short* AO  = (unsigned short*)ws;  ws += XB;
  float* ctab = (float*)ws;  ws += (size_t)SEQ * 32 * 4;
  float* stab = (float*)ws;  ws += (size_t)SEQ * 32 * 4;

  cvt_f32_bf16<<<(M_TOT * D_MODEL / 4) / 256, 256, 0, stream>>>(x, Xb, M_TOT * D_MODEL / 4);
  cvt_f32_bf16<<<(D_MODEL * D_MODEL / 4) / 256, 256, 0, stream>>>(qw, Wqb, D_MODEL * D_MODEL / 4);
  cvt_f32_bf16<<<(D_MODEL * D_MODEL / 4) / 256, 256, 0, stream>>>(kw, Wkb, D_MODEL * D_MODEL / 4);
  cvt_f32_bf16<<<(D_MODEL * D_MODEL / 4) / 256, 256, 0, stream>>>(vw, Wvb, D_MODEL * D_MODEL / 4);
  cvt_f32_bf16<<<(D_MODEL * D_MODEL / 4) / 256, 256, 0, stream>>>(ow, Wob, D_MODEL * D_MODEL / 4);
  rope_tables<<<(SEQ * 32) / 256, 256, 0, stream>>>(ctab, stab);

  // merged QKV projection: N = 3072
  gemm2<128, 128, 0><<<dim3(3072 / 128, M_TOT / 128), 256, 0, stream>>>(
      Xb, Wqb, Qr, Kr, Vt, nullptr, ctab, stab);

  attn_kernel<<<dim3(BATCH * 16, 32), 128, 0, stream>>>(Qr, Kr, Vt, AO);

  // final projection: N = 1024, 128x64 tile -> 512 blocks
  gemm2<128, 64, 2><<<dim3(D_MODEL / 64, M_TOT / 128), 256, 0, stream>>>(
      AO, Wob, nullptr, nullptr, nullptr, (float*)d_out, nullptr, nullptr);
}

// Round 7
// 144.106 us; speedup vs baseline: 1.6130x; 1.0416x over previous
//
#include <hip/hip_runtime.h>
#include <math.h>

typedef __attribute__((ext_vector_type(8))) short bf16x8;
typedef __attribute__((ext_vector_type(4))) float f32x4;

static constexpr int D_MODEL = 1024;
static constexpr int SEQ = 2048;
static constexpr int BATCH = 2;
static constexpr int M_TOT = BATCH * SEQ;   // 4096

__device__ __forceinline__ unsigned short f2bf(float f) {
  unsigned int u = __builtin_bit_cast(unsigned int, f);
  u += 0x7fffu + ((u >> 16) & 1u);   // round-to-nearest-even
  return (unsigned short)(u >> 16);
}

// async global -> LDS, 16B per lane.  dst must be wave-uniform base (HW: base + lane*16).
__device__ __forceinline__ void gld16(const unsigned short* g, unsigned short* l) {
  __builtin_amdgcn_global_load_lds(
      (const __attribute__((address_space(1))) unsigned int*)g,
      (__attribute__((address_space(3))) unsigned int*)l, 16, 0, 0);
}

// ---------------- prep: fp32 -> bf16 (vectorized) ----------------
__global__ void cvt_f32_bf16(const float* __restrict__ src,
                             unsigned short* __restrict__ dst, int n4) {
  int i = blockIdx.x * blockDim.x + threadIdx.x;
  if (i >= n4) return;
  const float4 v = reinterpret_cast<const float4*>(src)[i];
  ushort4 o;
  o.x = f2bf(v.x); o.y = f2bf(v.y); o.z = f2bf(v.z); o.w = f2bf(v.w);
  reinterpret_cast<ushort4*>(dst)[i] = o;
}

// all 4 weights in one dispatch; dst regions are contiguous (Wq|Wk|Wv|Wo).
__global__ void cvt_weights(const float* __restrict__ qw, const float* __restrict__ kw,
                            const float* __restrict__ vw, const float* __restrict__ ow,
                            unsigned short* __restrict__ dst) {
  int i = blockIdx.x * blockDim.x + threadIdx.x;   // over 4 * 2^18 float4 groups
  const int which = i >> 18;
  const int off = i & 262143;
  const float* src = (which == 0) ? qw : (which == 1) ? kw : (which == 2) ? vw : ow;
  const float4 v = reinterpret_cast<const float4*>(src)[off];
  ushort4 o;
  o.x = f2bf(v.x); o.y = f2bf(v.y); o.z = f2bf(v.z); o.w = f2bf(v.w);
  reinterpret_cast<ushort4*>(dst)[i] = o;
}

// ---------------- prep: RoPE cos/sin tables [SEQ][32] ----------------
__global__ void rope_tables(float* __restrict__ ctab, float* __restrict__ stab) {
  int idx = blockIdx.x * blockDim.x + threadIdx.x;
  int s = idx >> 5;
  int p = idx & 31;
  float inv_freq = powf(10000.0f, -(float)p / 32.0f);
  float ang = (float)s * inv_freq;
  ctab[idx] = cosf(ang);
  stab[idx] = sinf(ang);
}

// ---------------- GEMM (m97 structure): C[M][N] = A @ W^T ----------------
// (unchanged — keep bisectable)
template <int BM, int BN, int MODE>
__global__ __launch_bounds__(256, 2)
void gemm2(const unsigned short* __restrict__ A,
           const unsigned short* __restrict__ W,
           unsigned short* __restrict__ Qd,
           unsigned short* __restrict__ Kd,
           unsigned short* __restrict__ Vd,
           float* __restrict__ Fd,
           const float* __restrict__ ctab,
           const float* __restrict__ stab) {
  constexpr int MI = BM / 32, NI = BN / 32;
  __shared__ __align__(16) unsigned short As[BM * 32];
  __shared__ __align__(16) unsigned short Bs[BN * 32];
  const int tid  = threadIdx.x;
  const int lane = tid & 63;
  const int wave = tid >> 6;
  const int wm = wave >> 1, wn = wave & 1;
  const int m0 = blockIdx.y * BM;
  const int n0 = blockIdx.x * BN;
  const int lr = lane & 15, lg = lane >> 4;

  f32x4 acc[MI][NI] = {};

  for (int kt = 0; kt < D_MODEL / 32; ++kt) {
    const int k0 = kt * 32;
#pragma unroll
    for (int rr = 0; rr < BM / 64; ++rr) {
      const int flat = (rr * 256 + tid) * 8;
      const int row = flat >> 5, col = flat & 31;
      gld16(&A[(size_t)(m0 + row) * D_MODEL + k0 + col], &As[(rr * 4 + wave) * 512]);
    }
#pragma unroll
    for (int rr = 0; rr < BN / 64; ++rr) {
      const int flat = (rr * 256 + tid) * 8;
      const int row = flat >> 5, col = flat & 31;
      gld16(&W[(size_t)(n0 + row) * D_MODEL + k0 + col], &Bs[(rr * 4 + wave) * 512]);
    }
    __syncthreads();
    bf16x8 af[MI], bfr[NI];
#pragma unroll
    for (int i = 0; i < MI; ++i)
      af[i] = *reinterpret_cast<const bf16x8*>(&As[(wm * (BM / 2) + i * 16 + lr) * 32 + lg * 8]);
#pragma unroll
    for (int j = 0; j < NI; ++j)
      bfr[j] = *reinterpret_cast<const bf16x8*>(&Bs[(wn * (BN / 2) + j * 16 + lr) * 32 + lg * 8]);
#pragma unroll
    for (int i = 0; i < MI; ++i)
#pragma unroll
      for (int j = 0; j < NI; ++j)
        acc[i][j] = __builtin_amdgcn_mfma_f32_16x16x32_bf16(af[i], bfr[j], acc[i][j], 0, 0, 0);
    __syncthreads();
  }

  // epilogue.  C/D: col = lane&15, row = (lane>>4)*4 + reg
#pragma unroll
  for (int i = 0; i < MI; ++i) {
#pragma unroll
    for (int j = 0; j < NI; ++j) {
#pragma unroll
      for (int r = 0; r < 4; ++r) {
        float x = acc[i][j][r];
        const int gm = m0 + wm * (BM / 2) + i * 16 + lg * 4 + r;
        const int gc = n0 + wn * (BN / 2) + j * 16 + lr;
        if constexpr (MODE == 2) {
          Fd[(size_t)gm * D_MODEL + gc] = x;
        } else {
          const int b = gm >> 11, s = gm & 2047;
          const int t = gc >> 10, c = gc & 1023;
          const int n = c >> 6, h = c & 63;
          if (t < 2) {  // Q or K: fused RoPE
            const float co = ctab[s * 32 + (h >> 1)];
            const float sn = stab[s * 32 + (h >> 1)];
            const float part = __shfl_xor(x, 1, 64);
            x = (h & 1) ? (part * sn + x * co) : (x * co - part * sn);
            unsigned short* dst = (t == 0) ? Qd : Kd;
            dst[(size_t)((b * 16 + n) * SEQ + s) * 64 + h] = f2bf(x);
          } else {      // V transposed [bn][h][s]
            Vd[(size_t)((b * 16 + n) * 64 + h) * SEQ + s] = f2bf(x);
          }
        }
      }
    }
  }
}

// ---------------- flash attention v7: counted-vmcnt pipeline + paired blocks ----------------
// Block = 4 waves, processes q-blocks pr and 15-pr sequentially (2j+2 + 2(15-j)+2 = 34
// k-tiles for EVERY block -> perfect balance).  K/V 64x64 tiles staged once per block
// (XOR-swizzled source, linear LDS dst), double-buffered with counted vmcnt(4) waits and
// RAW s_barrier (never __syncthreads -> no forced vmcnt(0) drain).  Unnormalized exp,
// deferred row-sum.  grid: (32 bn, 8 pr) -> 256 uniform blocks, same-bn blocks same XCD.
__global__ __launch_bounds__(256, 1)
void attn_kernel(const unsigned short* __restrict__ Q,
                 const unsigned short* __restrict__ K,
                 const unsigned short* __restrict__ Vt,
                 unsigned short* __restrict__ AO) {
  __shared__ __align__(16) unsigned short Ksh[2][4096];  // [buf][64 x 64] swizzled
  __shared__ __align__(16) unsigned short Vsh[2][4096];
  __shared__ unsigned short Pl[4][32 * 72];
  const int bn   = blockIdx.x;
  const int pr   = blockIdx.y;                 // 0..7
  const int wave = threadIdx.x >> 6;
  const int lane = threadIdx.x & 63;
  const int lr = lane & 15, lg = lane >> 4;
  const unsigned short* Qh = Q  + (size_t)bn * SEQ * 64;
  const unsigned short* Kh = K  + (size_t)bn * SEQ * 64;
  const unsigned short* Vh = Vt + (size_t)bn * 64 * SEQ;
  unsigned short* Pw = &Pl[wave][0];
  const int b = bn >> 4, n = bn & 15;

  const int srow8 = lane >> 3;                 // row within 8-row chunk
  const int scolb = ((lane & 7) ^ srow8) * 8;  // inverse-swizzled source col (elements)

  // stage one 64x64 K tile + V tile into buf (4 gld16 per lane)
  auto stage = [&](int buf, int k0) {
#pragma unroll
    for (int c = 0; c < 2; ++c) {
      const int ch = wave * 2 + c;             // 8 chunks of 8 rows
      const int row = ch * 8 + srow8;
      gld16(&Kh[(size_t)(k0 + row) * 64 + scolb], &Ksh[buf][ch * 512]);
      gld16(&Vh[(size_t)row * SEQ + k0 + scolb], &Vsh[buf][ch * 512]);
    }
  };

  constexpr float KL2E = 0.125f * 1.44269504088896f;

  auto run_chunk = [&](int q0, int nt) {
    bf16x8 qf[2][2];
#pragma unroll
    for (int mi = 0; mi < 2; ++mi)
#pragma unroll
      for (int ks = 0; ks < 2; ++ks)
        qf[mi][ks] = *reinterpret_cast<const bf16x8*>(
            &Qh[(size_t)(q0 + mi * 16 + lr) * 64 + ks * 32 + lg * 8]);
    asm volatile("s_waitcnt vmcnt(0)" ::: "memory");  // clean slate for counted waits
    __builtin_amdgcn_sched_barrier(0);

    f32x4 o[2][4] = {};
    float lsum[2][4] = {};

    stage(0, 0);
    stage(1, 64);
    __builtin_amdgcn_sched_barrier(0);

    for (int t = 0; t < nt; ++t) {
      const int cur = t & 1;
      const int k0 = t * 64;
      // ---- stage(t) landed (counted: leave stage(t+1) in flight) ----
      if (t + 1 < nt) { asm volatile("s_waitcnt vmcnt(4)" ::: "memory"); }
      else            { asm volatile("s_waitcnt vmcnt(0)" ::: "memory"); }
      __builtin_amdgcn_s_barrier();            // all waves' stage(t) visible
      __builtin_amdgcn_sched_barrier(0);

      const unsigned short* Kc = &Ksh[cur][0];
      const unsigned short* Vc = &Vsh[cur][0];

      // ---- K frags (XOR-swizzled read) + QK^T ----
      bf16x8 kf[4][2];
#pragma unroll
      for (int nj = 0; nj < 4; ++nj)
#pragma unroll
        for (int ks = 0; ks < 2; ++ks) {
          const int R = nj * 16 + lr;
          const int p = (ks * 4 + lg) ^ (R & 7);
          kf[nj][ks] = *reinterpret_cast<const bf16x8*>(&Kc[R * 64 + p * 8]);
        }
      f32x4 sf[2][4] = {};
#pragma unroll
      for (int nj = 0; nj < 4; ++nj)
#pragma unroll
        for (int ks = 0; ks < 2; ++ks)
#pragma unroll
          for (int mi = 0; mi < 2; ++mi)
            sf[mi][nj] = __builtin_amdgcn_mfma_f32_16x16x32_bf16(qf[mi][ks], kf[nj][ks], sf[mi][nj], 0, 0, 0);

      // ---- p = exp2(s*KL2E); mask only boundary tiles; P -> LDS ----
      if (k0 + 63 <= q0) {
#pragma unroll
        for (int mi = 0; mi < 2; ++mi)
#pragma unroll
          for (int nj = 0; nj < 4; ++nj)
#pragma unroll
            for (int r = 0; r < 4; ++r) {
              const float p = exp2f(sf[mi][nj][r] * KL2E);
              lsum[mi][r] += p;
              Pw[(mi * 16 + lg * 4 + r) * 72 + nj * 16 + lr] = f2bf(p);
            }
      } else {
#pragma unroll
        for (int mi = 0; mi < 2; ++mi)
#pragma unroll
          for (int nj = 0; nj < 4; ++nj)
#pragma unroll
            for (int r = 0; r < 4; ++r) {
              const int qrow = q0 + mi * 16 + lg * 4 + r;
              const int kcol = k0 + nj * 16 + lr;
              const float p = (kcol <= qrow) ? exp2f(sf[mi][nj][r] * KL2E) : 0.0f;
              lsum[mi][r] += p;
              Pw[(mi * 16 + lg * 4 + r) * 72 + nj * 16 + lr] = f2bf(p);
            }
      }

      // ---- V frags (must complete before barrier2 frees the buffer) ----
      bf16x8 vf[2][4];
#pragma unroll
      for (int ks2 = 0; ks2 < 2; ++ks2)
#pragma unroll
        for (int hf = 0; hf < 4; ++hf) {
          const int R = hf * 16 + lr;
          const int p = (ks2 * 4 + lg) ^ (R & 7);
          vf[ks2][hf] = *reinterpret_cast<const bf16x8*>(&Vc[R * 64 + p * 8]);
        }
      asm volatile("s_waitcnt lgkmcnt(0)" ::: "memory");
      __builtin_amdgcn_sched_barrier(0);
      __builtin_amdgcn_s_barrier();            // all waves done reading buf cur
      __builtin_amdgcn_sched_barrier(0);

      // ---- refill freed buffer (lands ~1.5 tiles from now) ----
      if (t + 2 < nt) stage(cur, (t + 2) * 64);
      __builtin_amdgcn_sched_barrier(0);

      // ---- P frags (per-wave buffer) + PV ----
      bf16x8 pf[2][2];
#pragma unroll
      for (int mi = 0; mi < 2; ++mi)
#pragma unroll
        for (int ks2 = 0; ks2 < 2; ++ks2)
          pf[mi][ks2] = *reinterpret_cast<const bf16x8*>(&Pw[(mi * 16 + lr) * 72 + ks2 * 32 + lg * 8]);
#pragma unroll
      for (int ks2 = 0; ks2 < 2; ++ks2)
#pragma unroll
        for (int hf = 0; hf < 4; ++hf)
#pragma unroll
          for (int mi = 0; mi < 2; ++mi)
            o[mi][hf] = __builtin_amdgcn_mfma_f32_16x16x32_bf16(pf[mi][ks2], vf[ks2][hf], o[mi][hf], 0, 0, 0);
    }

    // ---- deferred row-sum reduce + normalize + store ----
#pragma unroll
    for (int mi = 0; mi < 2; ++mi)
#pragma unroll
      for (int r = 0; r < 4; ++r) {
        float s = lsum[mi][r];
#pragma unroll
        for (int d = 1; d < 16; d <<= 1) s += __shfl_xor(s, d, 64);
        const float inv = 1.0f / s;
        const int srow = q0 + mi * 16 + lg * 4 + r;
#pragma unroll
        for (int hf = 0; hf < 4; ++hf) {
          const int h = hf * 16 + lr;
          AO[(size_t)(b * SEQ + srow) * D_MODEL + n * 64 + h] = f2bf(o[mi][hf][r] * inv);
        }
      }
  };

  const int ja = pr, jb = 15 - pr;
  run_chunk(ja * 128 + wave * 32, 2 * ja + 2);   // light half
  run_chunk(jb * 128 + wave * 32, 2 * jb + 2);   // heavy half  (total = 34 tiles, uniform)
}

// ---------------- launch ----------------
extern "C" void kernel_launch(void* const* d_in, const int* in_sizes, int n_in,
                              void* d_out, int out_size, void* d_ws, size_t ws_size,
                              hipStream_t stream) {
  const float* qw = (const float*)d_in[0];
  const float* kw = (const float*)d_in[1];
  const float* vw = (const float*)d_in[2];
  const float* ow = (const float*)d_in[3];
  const float* x  = (const float*)d_in[4];

  char* ws = (char*)d_ws;
  const size_t XB = (size_t)M_TOT * D_MODEL * 2;      // 8 MB
  const size_t WB = (size_t)D_MODEL * D_MODEL * 2;    // 2 MB
  unsigned short* Xb  = (unsigned short*)ws;  ws += XB;
  unsigned short* Wqb = (unsigned short*)ws;  ws += WB;  // Wq|Wk|Wv|Wo contiguous
  unsigned short* Wkb = (unsigned short*)ws;  ws += WB;
  unsigned short* Wvb = (unsigned short*)ws;  ws += WB;
  unsigned short* Wob = (unsigned short*)ws;  ws += WB;
  unsigned short* Qr  = (unsigned short*)ws;  ws += XB;
  unsigned short* Kr  = (unsigned short*)ws;  ws += XB;
  unsigned short* Vt  = (unsigned short*)ws;  ws += XB;
  unsigned short* AO  = (unsigned short*)ws;  ws += XB;
  float* ctab = (float*)ws;  ws += (size_t)SEQ * 32 * 4;
  float* stab = (float*)ws;  ws += (size_t)SEQ * 32 * 4;

  cvt_f32_bf16<<<(M_TOT * D_MODEL / 4) / 256, 256, 0, stream>>>(x, Xb, M_TOT * D_MODEL / 4);
  cvt_weights<<<(4 * D_MODEL * D_MODEL / 4) / 256, 256, 0, stream>>>(qw, kw, vw, ow, Wqb);
  rope_tables<<<(SEQ * 32) / 256, 256, 0, stream>>>(ctab, stab);

  // merged QKV projection: N = 3072
  gemm2<128, 128, 0><<<dim3(3072 / 128, M_TOT / 128), 256, 0, stream>>>(
      Xb, Wqb, Qr, Kr, Vt, nullptr, ctab, stab);

  attn_kernel<<<dim3(BATCH * 16, 8), 256, 0, stream>>>(Qr, Kr, Vt, AO);

  // final projection: N = 1024, 128x64 tile -> 512 blocks
  gemm2<128, 64, 2><<<dim3(D_MODEL / 64, M_TOT / 128), 256, 0, stream>>>(
      AO, Wob, nullptr, nullptr, nullptr, (float*)d_out, nullptr, nullptr);
}

// Round 8
// 130.200 us; speedup vs baseline: 1.7853x; 1.1068x over previous
//
#include <hip/hip_runtime.h>
#include <math.h>

typedef __attribute__((ext_vector_type(8))) short bf16x8;
typedef __attribute__((ext_vector_type(4))) float f32x4;

static constexpr int D_MODEL = 1024;
static constexpr int SEQ = 2048;
static constexpr int BATCH = 2;
static constexpr int M_TOT = BATCH * SEQ;   // 4096

__device__ __forceinline__ unsigned short f2bf(float f) {
  unsigned int u = __builtin_bit_cast(unsigned int, f);
  u += 0x7fffu + ((u >> 16) & 1u);   // round-to-nearest-even
  return (unsigned short)(u >> 16);
}

// async global -> LDS, 16B per lane.  dst must be wave-uniform base (HW: base + lane*16).
__device__ __forceinline__ void gld16(const unsigned short* g, unsigned short* l) {
  __builtin_amdgcn_global_load_lds(
      (const __attribute__((address_space(1))) unsigned int*)g,
      (__attribute__((address_space(3))) unsigned int*)l, 16, 0, 0);
}

// ---------------- prep: fp32 -> bf16 (vectorized) ----------------
__global__ void cvt_f32_bf16(const float* __restrict__ src,
                             unsigned short* __restrict__ dst, int n4) {
  int i = blockIdx.x * blockDim.x + threadIdx.x;
  if (i >= n4) return;
  const float4 v = reinterpret_cast<const float4*>(src)[i];
  ushort4 o;
  o.x = f2bf(v.x); o.y = f2bf(v.y); o.z = f2bf(v.z); o.w = f2bf(v.w);
  reinterpret_cast<ushort4*>(dst)[i] = o;
}

// all 4 weights in one dispatch; dst regions are contiguous (Wq|Wk|Wv|Wo).
__global__ void cvt_weights(const float* __restrict__ qw, const float* __restrict__ kw,
                            const float* __restrict__ vw, const float* __restrict__ ow,
                            unsigned short* __restrict__ dst) {
  int i = blockIdx.x * blockDim.x + threadIdx.x;   // over 4 * 2^18 float4 groups
  const int which = i >> 18;
  const int off = i & 262143;
  const float* src = (which == 0) ? qw : (which == 1) ? kw : (which == 2) ? vw : ow;
  const float4 v = reinterpret_cast<const float4*>(src)[off];
  ushort4 o;
  o.x = f2bf(v.x); o.y = f2bf(v.y); o.z = f2bf(v.z); o.w = f2bf(v.w);
  reinterpret_cast<ushort4*>(dst)[i] = o;
}

// ---------------- prep: RoPE cos/sin tables [SEQ][32] ----------------
__global__ void rope_tables(float* __restrict__ ctab, float* __restrict__ stab) {
  int idx = blockIdx.x * blockDim.x + threadIdx.x;
  int s = idx >> 5;
  int p = idx & 31;
  float inv_freq = powf(10000.0f, -(float)p / 32.0f);
  float ang = (float)s * inv_freq;
  ctab[idx] = cosf(ang);
  stab[idx] = sinf(ang);
}

// ---------------- GEMM (m97 structure): C[M][N] = A @ W^T ----------------
// (unchanged — keep bisectable)
template <int BM, int BN, int MODE>
__global__ __launch_bounds__(256, 2)
void gemm2(const unsigned short* __restrict__ A,
           const unsigned short* __restrict__ W,
           unsigned short* __restrict__ Qd,
           unsigned short* __restrict__ Kd,
           unsigned short* __restrict__ Vd,
           float* __restrict__ Fd,
           const float* __restrict__ ctab,
           const float* __restrict__ stab) {
  constexpr int MI = BM / 32, NI = BN / 32;
  __shared__ __align__(16) unsigned short As[BM * 32];
  __shared__ __align__(16) unsigned short Bs[BN * 32];
  const int tid  = threadIdx.x;
  const int lane = tid & 63;
  const int wave = tid >> 6;
  const int wm = wave >> 1, wn = wave & 1;
  const int m0 = blockIdx.y * BM;
  const int n0 = blockIdx.x * BN;
  const int lr = lane & 15, lg = lane >> 4;

  f32x4 acc[MI][NI] = {};

  for (int kt = 0; kt < D_MODEL / 32; ++kt) {
    const int k0 = kt * 32;
#pragma unroll
    for (int rr = 0; rr < BM / 64; ++rr) {
      const int flat = (rr * 256 + tid) * 8;
      const int row = flat >> 5, col = flat & 31;
      gld16(&A[(size_t)(m0 + row) * D_MODEL + k0 + col], &As[(rr * 4 + wave) * 512]);
    }
#pragma unroll
    for (int rr = 0; rr < BN / 64; ++rr) {
      const int flat = (rr * 256 + tid) * 8;
      const int row = flat >> 5, col = flat & 31;
      gld16(&W[(size_t)(n0 + row) * D_MODEL + k0 + col], &Bs[(rr * 4 + wave) * 512]);
    }
    __syncthreads();
    bf16x8 af[MI], bfr[NI];
#pragma unroll
    for (int i = 0; i < MI; ++i)
      af[i] = *reinterpret_cast<const bf16x8*>(&As[(wm * (BM / 2) + i * 16 + lr) * 32 + lg * 8]);
#pragma unroll
    for (int j = 0; j < NI; ++j)
      bfr[j] = *reinterpret_cast<const bf16x8*>(&Bs[(wn * (BN / 2) + j * 16 + lr) * 32 + lg * 8]);
#pragma unroll
    for (int i = 0; i < MI; ++i)
#pragma unroll
      for (int j = 0; j < NI; ++j)
        acc[i][j] = __builtin_amdgcn_mfma_f32_16x16x32_bf16(af[i], bfr[j], acc[i][j], 0, 0, 0);
    __syncthreads();
  }

  // epilogue.  C/D: col = lane&15, row = (lane>>4)*4 + reg
#pragma unroll
  for (int i = 0; i < MI; ++i) {
#pragma unroll
    for (int j = 0; j < NI; ++j) {
#pragma unroll
      for (int r = 0; r < 4; ++r) {
        float x = acc[i][j][r];
        const int gm = m0 + wm * (BM / 2) + i * 16 + lg * 4 + r;
        const int gc = n0 + wn * (BN / 2) + j * 16 + lr;
        if constexpr (MODE == 2) {
          Fd[(size_t)gm * D_MODEL + gc] = x;
        } else {
          const int b = gm >> 11, s = gm & 2047;
          const int t = gc >> 10, c = gc & 1023;
          const int n = c >> 6, h = c & 63;
          if (t < 2) {  // Q or K: fused RoPE
            const float co = ctab[s * 32 + (h >> 1)];
            const float sn = stab[s * 32 + (h >> 1)];
            const float part = __shfl_xor(x, 1, 64);
            x = (h & 1) ? (part * sn + x * co) : (x * co - part * sn);
            unsigned short* dst = (t == 0) ? Qd : Kd;
            dst[(size_t)((b * 16 + n) * SEQ + s) * 64 + h] = f2bf(x);
          } else {      // V transposed [bn][h][s]
            Vd[(size_t)((b * 16 + n) * 64 + h) * SEQ + s] = f2bf(x);
          }
        }
      }
    }
  }
}

// ---------------- flash attention v8: counted-vmcnt pipeline + TLP ----------------
// Round-7 pipeline body (counted vmcnt(4), raw s_barrier, block-shared swizzled LDS
// K/V) but 512 independent blocks (32 bn x 16 q-blocks, heavy-first) -> 2-3 blocks/CU
// of TLP to hide the remaining latency.  4 waves/block, q-block=128 rows, nt=2j+2.
__global__ __launch_bounds__(256, 2)
void attn_kernel(const unsigned short* __restrict__ Q,
                 const unsigned short* __restrict__ K,
                 const unsigned short* __restrict__ Vt,
                 unsigned short* __restrict__ AO) {
  __shared__ __align__(16) unsigned short Ksh[2][4096];  // [buf][64 x 64] swizzled
  __shared__ __align__(16) unsigned short Vsh[2][4096];
  __shared__ unsigned short Pl[4][32 * 72];
  const int bn   = blockIdx.x;
  const int j    = (gridDim.y - 1) - blockIdx.y;   // heavy-first: j=15 dispatched first
  const int wave = threadIdx.x >> 6;
  const int lane = threadIdx.x & 63;
  const int lr = lane & 15, lg = lane >> 4;
  const int q0 = j * 128 + wave * 32;
  const unsigned short* Qh = Q  + (size_t)bn * SEQ * 64;
  const unsigned short* Kh = K  + (size_t)bn * SEQ * 64;
  const unsigned short* Vh = Vt + (size_t)bn * 64 * SEQ;
  unsigned short* Pw = &Pl[wave][0];
  const int b = bn >> 4, n = bn & 15;

  const int srow8 = lane >> 3;                 // row within 8-row chunk
  const int scolb = ((lane & 7) ^ srow8) * 8;  // inverse-swizzled source col (elements)

  // stage one 64x64 K tile + V tile into buf (4 gld16 per lane)
  auto stage = [&](int buf, int k0) {
#pragma unroll
    for (int c = 0; c < 2; ++c) {
      const int ch = wave * 2 + c;             // 8 chunks of 8 rows
      const int row = ch * 8 + srow8;
      gld16(&Kh[(size_t)(k0 + row) * 64 + scolb], &Ksh[buf][ch * 512]);
      gld16(&Vh[(size_t)row * SEQ + k0 + scolb], &Vsh[buf][ch * 512]);
    }
  };

  constexpr float KL2E = 0.125f * 1.44269504088896f;
  const int nt = 2 * j + 2;                    // causal k-tiles of 64

  bf16x8 qf[2][2];
#pragma unroll
  for (int mi = 0; mi < 2; ++mi)
#pragma unroll
    for (int ks = 0; ks < 2; ++ks)
      qf[mi][ks] = *reinterpret_cast<const bf16x8*>(
          &Qh[(size_t)(q0 + mi * 16 + lr) * 64 + ks * 32 + lg * 8]);
  asm volatile("s_waitcnt vmcnt(0)" ::: "memory");  // clean slate for counted waits
  __builtin_amdgcn_sched_barrier(0);

  f32x4 o[2][4] = {};
  float lsum[2][4] = {};

  stage(0, 0);
  stage(1, 64);
  __builtin_amdgcn_sched_barrier(0);

  for (int t = 0; t < nt; ++t) {
    const int cur = t & 1;
    const int k0 = t * 64;
    // ---- stage(t) landed (counted: leave stage(t+1) in flight) ----
    if (t + 1 < nt) { asm volatile("s_waitcnt vmcnt(4)" ::: "memory"); }
    else            { asm volatile("s_waitcnt vmcnt(0)" ::: "memory"); }
    __builtin_amdgcn_s_barrier();            // all waves' stage(t) visible
    __builtin_amdgcn_sched_barrier(0);

    const unsigned short* Kc = &Ksh[cur][0];
    const unsigned short* Vc = &Vsh[cur][0];

    // ---- K frags (XOR-swizzled read) + QK^T ----
    bf16x8 kf[4][2];
#pragma unroll
    for (int nj = 0; nj < 4; ++nj)
#pragma unroll
      for (int ks = 0; ks < 2; ++ks) {
        const int R = nj * 16 + lr;
        const int p = (ks * 4 + lg) ^ (R & 7);
        kf[nj][ks] = *reinterpret_cast<const bf16x8*>(&Kc[R * 64 + p * 8]);
      }
    f32x4 sf[2][4] = {};
    __builtin_amdgcn_s_setprio(1);
#pragma unroll
    for (int nj = 0; nj < 4; ++nj)
#pragma unroll
      for (int ks = 0; ks < 2; ++ks)
#pragma unroll
        for (int mi = 0; mi < 2; ++mi)
          sf[mi][nj] = __builtin_amdgcn_mfma_f32_16x16x32_bf16(qf[mi][ks], kf[nj][ks], sf[mi][nj], 0, 0, 0);
    __builtin_amdgcn_s_setprio(0);

    // ---- p = exp2(s*KL2E); mask only boundary tiles; P -> LDS ----
    if (k0 + 63 <= q0) {
#pragma unroll
      for (int mi = 0; mi < 2; ++mi)
#pragma unroll
        for (int nj = 0; nj < 4; ++nj)
#pragma unroll
          for (int r = 0; r < 4; ++r) {
            const float p = __builtin_amdgcn_exp2f(sf[mi][nj][r] * KL2E);
            lsum[mi][r] += p;
            Pw[(mi * 16 + lg * 4 + r) * 72 + nj * 16 + lr] = f2bf(p);
          }
    } else {
#pragma unroll
      for (int mi = 0; mi < 2; ++mi)
#pragma unroll
        for (int nj = 0; nj < 4; ++nj)
#pragma unroll
          for (int r = 0; r < 4; ++r) {
            const int qrow = q0 + mi * 16 + lg * 4 + r;
            const int kcol = k0 + nj * 16 + lr;
            const float p = (kcol <= qrow) ? __builtin_amdgcn_exp2f(sf[mi][nj][r] * KL2E) : 0.0f;
            lsum[mi][r] += p;
            Pw[(mi * 16 + lg * 4 + r) * 72 + nj * 16 + lr] = f2bf(p);
          }
    }

    // ---- V frags (must complete before barrier2 frees the buffer) ----
    bf16x8 vf[2][4];
#pragma unroll
    for (int ks2 = 0; ks2 < 2; ++ks2)
#pragma unroll
      for (int hf = 0; hf < 4; ++hf) {
        const int R = hf * 16 + lr;
        const int p = (ks2 * 4 + lg) ^ (R & 7);
        vf[ks2][hf] = *reinterpret_cast<const bf16x8*>(&Vc[R * 64 + p * 8]);
      }
    asm volatile("s_waitcnt lgkmcnt(0)" ::: "memory");
    __builtin_amdgcn_sched_barrier(0);
    __builtin_amdgcn_s_barrier();            // all waves done reading buf cur
    __builtin_amdgcn_sched_barrier(0);

    // ---- refill freed buffer (lands ~1.5 tiles from now) ----
    if (t + 2 < nt) stage(cur, (t + 2) * 64);
    __builtin_amdgcn_sched_barrier(0);

    // ---- P frags (per-wave buffer) + PV ----
    bf16x8 pf[2][2];
#pragma unroll
    for (int mi = 0; mi < 2; ++mi)
#pragma unroll
      for (int ks2 = 0; ks2 < 2; ++ks2)
        pf[mi][ks2] = *reinterpret_cast<const bf16x8*>(&Pw[(mi * 16 + lr) * 72 + ks2 * 32 + lg * 8]);
    __builtin_amdgcn_s_setprio(1);
#pragma unroll
    for (int ks2 = 0; ks2 < 2; ++ks2)
#pragma unroll
      for (int hf = 0; hf < 4; ++hf)
#pragma unroll
        for (int mi = 0; mi < 2; ++mi)
          o[mi][hf] = __builtin_amdgcn_mfma_f32_16x16x32_bf16(pf[mi][ks2], vf[ks2][hf], o[mi][hf], 0, 0, 0);
    __builtin_amdgcn_s_setprio(0);
  }

  // ---- deferred row-sum reduce + normalize + store ----
#pragma unroll
  for (int mi = 0; mi < 2; ++mi)
#pragma unroll
    for (int r = 0; r < 4; ++r) {
      float s = lsum[mi][r];
#pragma unroll
      for (int d = 1; d < 16; d <<= 1) s += __shfl_xor(s, d, 64);
      const float inv = 1.0f / s;
      const int srow = q0 + mi * 16 + lg * 4 + r;
#pragma unroll
      for (int hf = 0; hf < 4; ++hf) {
        const int h = hf * 16 + lr;
        AO[(size_t)(b * SEQ + srow) * D_MODEL + n * 64 + h] = f2bf(o[mi][hf][r] * inv);
      }
    }
}

// ---------------- launch ----------------
extern "C" void kernel_launch(void* const* d_in, const int* in_sizes, int n_in,
                              void* d_out, int out_size, void* d_ws, size_t ws_size,
                              hipStream_t stream) {
  const float* qw = (const float*)d_in[0];
  const float* kw = (const float*)d_in[1];
  const float* vw = (const float*)d_in[2];
  const float* ow = (const float*)d_in[3];
  const float* x  = (const float*)d_in[4];

  char* ws = (char*)d_ws;
  const size_t XB = (size_t)M_TOT * D_MODEL * 2;      // 8 MB
  const size_t WB = (size_t)D_MODEL * D_MODEL * 2;    // 2 MB
  unsigned short* Xb  = (unsigned short*)ws;  ws += XB;
  unsigned short* Wqb = (unsigned short*)ws;  ws += WB;  // Wq|Wk|Wv|Wo contiguous
  unsigned short* Wkb = (unsigned short*)ws;  ws += WB;
  unsigned short* Wvb = (unsigned short*)ws;  ws += WB;
  unsigned short* Wob = (unsigned short*)ws;  ws += WB;
  unsigned short* Qr  = (unsigned short*)ws;  ws += XB;
  unsigned short* Kr  = (unsigned short*)ws;  ws += XB;
  unsigned short* Vt  = (unsigned short*)ws;  ws += XB;
  unsigned short* AO  = (unsigned short*)ws;  ws += XB;
  float* ctab = (float*)ws;  ws += (size_t)SEQ * 32 * 4;
  float* stab = (float*)ws;  ws += (size_t)SEQ * 32 * 4;

  cvt_f32_bf16<<<(M_TOT * D_MODEL / 4) / 256, 256, 0, stream>>>(x, Xb, M_TOT * D_MODEL / 4);
  cvt_weights<<<(4 * D_MODEL * D_MODEL / 4) / 256, 256, 0, stream>>>(qw, kw, vw, ow, Wqb);
  rope_tables<<<(SEQ * 32) / 256, 256, 0, stream>>>(ctab, stab);

  // merged QKV projection: N = 3072
  gemm2<128, 128, 0><<<dim3(3072 / 128, M_TOT / 128), 256, 0, stream>>>(
      Xb, Wqb, Qr, Kr, Vt, nullptr, ctab, stab);

  attn_kernel<<<dim3(BATCH * 16, 16), 256, 0, stream>>>(Qr, Kr, Vt, AO);

  // final projection: N = 1024, 128x64 tile -> 512 blocks
  gemm2<128, 64, 2><<<dim3(D_MODEL / 64, M_TOT / 128), 256, 0, stream>>>(
      AO, Wob, nullptr, nullptr, nullptr, (float*)d_out, nullptr, nullptr);
}

// Round 9
// 127.665 us; speedup vs baseline: 1.8207x; 1.0199x over previous
//
#include <hip/hip_runtime.h>
#include <math.h>

typedef __attribute__((ext_vector_type(8))) short bf16x8;
typedef __attribute__((ext_vector_type(4))) float f32x4;

static constexpr int D_MODEL = 1024;
static constexpr int SEQ = 2048;
static constexpr int BATCH = 2;
static constexpr int M_TOT = BATCH * SEQ;   // 4096

__device__ __forceinline__ unsigned short f2bf(float f) {
  unsigned int u = __builtin_bit_cast(unsigned int, f);
  u += 0x7fffu + ((u >> 16) & 1u);   // round-to-nearest-even
  return (unsigned short)(u >> 16);
}

// async global -> LDS, 16B per lane.  dst must be wave-uniform base (HW: base + lane*16).
__device__ __forceinline__ void gld16(const unsigned short* g, unsigned short* l) {
  __builtin_amdgcn_global_load_lds(
      (const __attribute__((address_space(1))) unsigned int*)g,
      (__attribute__((address_space(3))) unsigned int*)l, 16, 0, 0);
}

// ---------------- prep: fp32 -> bf16 (vectorized) ----------------
__global__ void cvt_f32_bf16(const float* __restrict__ src,
                             unsigned short* __restrict__ dst, int n4) {
  int i = blockIdx.x * blockDim.x + threadIdx.x;
  if (i >= n4) return;
  const float4 v = reinterpret_cast<const float4*>(src)[i];
  ushort4 o;
  o.x = f2bf(v.x); o.y = f2bf(v.y); o.z = f2bf(v.z); o.w = f2bf(v.w);
  reinterpret_cast<ushort4*>(dst)[i] = o;
}

// all 4 weights in one dispatch; dst regions are contiguous (Wq|Wk|Wv|Wo).
__global__ void cvt_weights(const float* __restrict__ qw, const float* __restrict__ kw,
                            const float* __restrict__ vw, const float* __restrict__ ow,
                            unsigned short* __restrict__ dst) {
  int i = blockIdx.x * blockDim.x + threadIdx.x;   // over 4 * 2^18 float4 groups
  const int which = i >> 18;
  const int off = i & 262143;
  const float* src = (which == 0) ? qw : (which == 1) ? kw : (which == 2) ? vw : ow;
  const float4 v = reinterpret_cast<const float4*>(src)[off];
  ushort4 o;
  o.x = f2bf(v.x); o.y = f2bf(v.y); o.z = f2bf(v.z); o.w = f2bf(v.w);
  reinterpret_cast<ushort4*>(dst)[i] = o;
}

// ---------------- prep: RoPE cos/sin tables [SEQ][32] ----------------
__global__ void rope_tables(float* __restrict__ ctab, float* __restrict__ stab) {
  int idx = blockIdx.x * blockDim.x + threadIdx.x;
  int s = idx >> 5;
  int p = idx & 31;
  float inv_freq = powf(10000.0f, -(float)p / 32.0f);
  float ang = (float)s * inv_freq;
  ctab[idx] = cosf(ang);
  stab[idx] = sinf(ang);
}

// ---------------- GEMM v2: double-buffered counted-vmcnt + swizzled LDS ----------------
// C[M][N] = A @ W^T.  A [M][1024] bf16, W [N][1024] bf16.  BK=32.
// LDS tile [row][32] swizzled: 16B-chunk c stored at c ^ ((row>>1)&3) -> frag reads
// are 2-way (free).  Staging pre-swizzles the GLOBAL source (gld16 dst stays linear).
// Pipeline: stage(kt+2) after read-complete barrier; counted vmcnt, never drain.
// MODE 0: merged QKV (N=3072) -> Q/K rope or V transposed.  MODE 2: fp32 out.
template <int BM, int BN, int MODE>
__global__ __launch_bounds__(256, 2)
void gemm2(const unsigned short* __restrict__ A,
           const unsigned short* __restrict__ W,
           unsigned short* __restrict__ Qd,
           unsigned short* __restrict__ Kd,
           unsigned short* __restrict__ Vd,
           float* __restrict__ Fd,
           const float* __restrict__ ctab,
           const float* __restrict__ stab) {
  constexpr int MI = BM / 32, NI = BN / 32;
  constexpr int NKT = D_MODEL / 32;            // 32 k-steps
  constexpr int LOADS = BM / 64 + BN / 64;     // gld16 per wave per stage
  __shared__ __align__(16) unsigned short As[2][BM * 32];
  __shared__ __align__(16) unsigned short Bs[2][BN * 32];
  const int tid  = threadIdx.x;
  const int lane = tid & 63;
  const int wave = tid >> 6;
  const int wm = wave >> 1, wn = wave & 1;
  const int m0 = blockIdx.y * BM;
  const int n0 = blockIdx.x * BN;
  const int lr = lane & 15, lg = lane >> 4;

  // staging: lane covers (row = ch*16 + lane>>2, chunk = lane&3); source col chunk
  // pre-swizzled so LDS(row,c) holds global(row, c ^ ((row>>1)&3)).
  const int srow = lane >> 2;
  const int scol = ((lane & 3) ^ ((lane >> 3) & 3)) * 8;

  auto stage = [&](int buf, int kt) {
    const int k0 = kt * 32;
#pragma unroll
    for (int rr = 0; rr < BM / 64; ++rr) {
      const int ch = rr * 4 + wave;
      gld16(&A[(size_t)(m0 + ch * 16 + srow) * D_MODEL + k0 + scol], &As[buf][ch * 512]);
    }
#pragma unroll
    for (int rr = 0; rr < BN / 64; ++rr) {
      const int ch = rr * 4 + wave;
      gld16(&W[(size_t)(n0 + ch * 16 + srow) * D_MODEL + k0 + scol], &Bs[buf][ch * 512]);
    }
  };

  f32x4 acc[MI][NI] = {};

  stage(0, 0);
  stage(1, 1);
  __builtin_amdgcn_sched_barrier(0);

  const int swz = (lg ^ ((lr >> 1) & 3)) * 8;  // frag-read chunk (row base mult of 16)

  for (int kt = 0; kt < NKT; ++kt) {
    const int cur = kt & 1;
    // ---- stage(kt) landed; leave stage(kt+1) in flight ----
    if (kt + 1 < NKT) {
      if constexpr (LOADS == 4) asm volatile("s_waitcnt vmcnt(4)" ::: "memory");
      else                      asm volatile("s_waitcnt vmcnt(3)" ::: "memory");
    } else {
      asm volatile("s_waitcnt vmcnt(0)" ::: "memory");
    }
    __builtin_amdgcn_s_barrier();
    __builtin_amdgcn_sched_barrier(0);

    bf16x8 af[MI], bfr[NI];
#pragma unroll
    for (int i = 0; i < MI; ++i)
      af[i] = *reinterpret_cast<const bf16x8*>(&As[cur][(wm * (BM / 2) + i * 16 + lr) * 32 + swz]);
#pragma unroll
    for (int j = 0; j < NI; ++j)
      bfr[j] = *reinterpret_cast<const bf16x8*>(&Bs[cur][(wn * (BN / 2) + j * 16 + lr) * 32 + swz]);
    asm volatile("s_waitcnt lgkmcnt(0)" ::: "memory");
    __builtin_amdgcn_sched_barrier(0);
    __builtin_amdgcn_s_barrier();            // all waves done reading buf cur
    __builtin_amdgcn_sched_barrier(0);

    // ---- refill freed buffer; lands during MFMA + next iteration ----
    if (kt + 2 < NKT) stage(cur, kt + 2);
    __builtin_amdgcn_sched_barrier(0);

#pragma unroll
    for (int i = 0; i < MI; ++i)
#pragma unroll
      for (int j = 0; j < NI; ++j)
        acc[i][j] = __builtin_amdgcn_mfma_f32_16x16x32_bf16(af[i], bfr[j], acc[i][j], 0, 0, 0);
  }

  // epilogue.  C/D: col = lane&15, row = (lane>>4)*4 + reg
#pragma unroll
  for (int i = 0; i < MI; ++i) {
#pragma unroll
    for (int j = 0; j < NI; ++j) {
#pragma unroll
      for (int r = 0; r < 4; ++r) {
        float x = acc[i][j][r];
        const int gm = m0 + wm * (BM / 2) + i * 16 + lg * 4 + r;
        const int gc = n0 + wn * (BN / 2) + j * 16 + lr;
        if constexpr (MODE == 2) {
          Fd[(size_t)gm * D_MODEL + gc] = x;
        } else {
          const int b = gm >> 11, s = gm & 2047;
          const int t = gc >> 10, c = gc & 1023;
          const int n = c >> 6, h = c & 63;
          if (t < 2) {  // Q or K: fused RoPE
            const float co = ctab[s * 32 + (h >> 1)];
            const float sn = stab[s * 32 + (h >> 1)];
            const float part = __shfl_xor(x, 1, 64);
            x = (h & 1) ? (part * sn + x * co) : (x * co - part * sn);
            unsigned short* dst = (t == 0) ? Qd : Kd;
            dst[(size_t)((b * 16 + n) * SEQ + s) * 64 + h] = f2bf(x);
          } else {      // V transposed [bn][h][s]
            Vd[(size_t)((b * 16 + n) * 64 + h) * SEQ + s] = f2bf(x);
          }
        }
      }
    }
  }
}

// ---------------- flash attention v8: counted-vmcnt pipeline + TLP (unchanged) ----------------
__global__ __launch_bounds__(256, 2)
void attn_kernel(const unsigned short* __restrict__ Q,
                 const unsigned short* __restrict__ K,
                 const unsigned short* __restrict__ Vt,
                 unsigned short* __restrict__ AO) {
  __shared__ __align__(16) unsigned short Ksh[2][4096];  // [buf][64 x 64] swizzled
  __shared__ __align__(16) unsigned short Vsh[2][4096];
  __shared__ unsigned short Pl[4][32 * 72];
  const int bn   = blockIdx.x;
  const int j    = (gridDim.y - 1) - blockIdx.y;   // heavy-first: j=15 dispatched first
  const int wave = threadIdx.x >> 6;
  const int lane = threadIdx.x & 63;
  const int lr = lane & 15, lg = lane >> 4;
  const int q0 = j * 128 + wave * 32;
  const unsigned short* Qh = Q  + (size_t)bn * SEQ * 64;
  const unsigned short* Kh = K  + (size_t)bn * SEQ * 64;
  const unsigned short* Vh = Vt + (size_t)bn * 64 * SEQ;
  unsigned short* Pw = &Pl[wave][0];
  const int b = bn >> 4, n = bn & 15;

  const int srow8 = lane >> 3;                 // row within 8-row chunk
  const int scolb = ((lane & 7) ^ srow8) * 8;  // inverse-swizzled source col (elements)

  // stage one 64x64 K tile + V tile into buf (4 gld16 per lane)
  auto stage = [&](int buf, int k0) {
#pragma unroll
    for (int c = 0; c < 2; ++c) {
      const int ch = wave * 2 + c;             // 8 chunks of 8 rows
      const int row = ch * 8 + srow8;
      gld16(&Kh[(size_t)(k0 + row) * 64 + scolb], &Ksh[buf][ch * 512]);
      gld16(&Vh[(size_t)row * SEQ + k0 + scolb], &Vsh[buf][ch * 512]);
    }
  };

  constexpr float KL2E = 0.125f * 1.44269504088896f;
  const int nt = 2 * j + 2;                    // causal k-tiles of 64

  bf16x8 qf[2][2];
#pragma unroll
  for (int mi = 0; mi < 2; ++mi)
#pragma unroll
    for (int ks = 0; ks < 2; ++ks)
      qf[mi][ks] = *reinterpret_cast<const bf16x8*>(
          &Qh[(size_t)(q0 + mi * 16 + lr) * 64 + ks * 32 + lg * 8]);
  asm volatile("s_waitcnt vmcnt(0)" ::: "memory");  // clean slate for counted waits
  __builtin_amdgcn_sched_barrier(0);

  f32x4 o[2][4] = {};
  float lsum[2][4] = {};

  stage(0, 0);
  stage(1, 64);
  __builtin_amdgcn_sched_barrier(0);

  for (int t = 0; t < nt; ++t) {
    const int cur = t & 1;
    const int k0 = t * 64;
    // ---- stage(t) landed (counted: leave stage(t+1) in flight) ----
    if (t + 1 < nt) { asm volatile("s_waitcnt vmcnt(4)" ::: "memory"); }
    else            { asm volatile("s_waitcnt vmcnt(0)" ::: "memory"); }
    __builtin_amdgcn_s_barrier();            // all waves' stage(t) visible
    __builtin_amdgcn_sched_barrier(0);

    const unsigned short* Kc = &Ksh[cur][0];
    const unsigned short* Vc = &Vsh[cur][0];

    // ---- K frags (XOR-swizzled read) + QK^T ----
    bf16x8 kf[4][2];
#pragma unroll
    for (int nj = 0; nj < 4; ++nj)
#pragma unroll
      for (int ks = 0; ks < 2; ++ks) {
        const int R = nj * 16 + lr;
        const int p = (ks * 4 + lg) ^ (R & 7);
        kf[nj][ks] = *reinterpret_cast<const bf16x8*>(&Kc[R * 64 + p * 8]);
      }
    f32x4 sf[2][4] = {};
    __builtin_amdgcn_s_setprio(1);
#pragma unroll
    for (int nj = 0; nj < 4; ++nj)
#pragma unroll
      for (int ks = 0; ks < 2; ++ks)
#pragma unroll
        for (int mi = 0; mi < 2; ++mi)
          sf[mi][nj] = __builtin_amdgcn_mfma_f32_16x16x32_bf16(qf[mi][ks], kf[nj][ks], sf[mi][nj], 0, 0, 0);
    __builtin_amdgcn_s_setprio(0);

    // ---- p = exp2(s*KL2E); mask only boundary tiles; P -> LDS ----
    if (k0 + 63 <= q0) {
#pragma unroll
      for (int mi = 0; mi < 2; ++mi)
#pragma unroll
        for (int nj = 0; nj < 4; ++nj)
#pragma unroll
          for (int r = 0; r < 4; ++r) {
            const float p = __builtin_amdgcn_exp2f(sf[mi][nj][r] * KL2E);
            lsum[mi][r] += p;
            Pw[(mi * 16 + lg * 4 + r) * 72 + nj * 16 + lr] = f2bf(p);
          }
    } else {
#pragma unroll
      for (int mi = 0; mi < 2; ++mi)
#pragma unroll
        for (int nj = 0; nj < 4; ++nj)
#pragma unroll
          for (int r = 0; r < 4; ++r) {
            const int qrow = q0 + mi * 16 + lg * 4 + r;
            const int kcol = k0 + nj * 16 + lr;
            const float p = (kcol <= qrow) ? __builtin_amdgcn_exp2f(sf[mi][nj][r] * KL2E) : 0.0f;
            lsum[mi][r] += p;
            Pw[(mi * 16 + lg * 4 + r) * 72 + nj * 16 + lr] = f2bf(p);
          }
    }

    // ---- V frags (must complete before barrier2 frees the buffer) ----
    bf16x8 vf[2][4];
#pragma unroll
    for (int ks2 = 0; ks2 < 2; ++ks2)
#pragma unroll
      for (int hf = 0; hf < 4; ++hf) {
        const int R = hf * 16 + lr;
        const int p = (ks2 * 4 + lg) ^ (R & 7);
        vf[ks2][hf] = *reinterpret_cast<const bf16x8*>(&Vc[R * 64 + p * 8]);
      }
    asm volatile("s_waitcnt lgkmcnt(0)" ::: "memory");
    __builtin_amdgcn_sched_barrier(0);
    __builtin_amdgcn_s_barrier();            // all waves done reading buf cur
    __builtin_amdgcn_sched_barrier(0);

    // ---- refill freed buffer (lands ~1.5 tiles from now) ----
    if (t + 2 < nt) stage(cur, (t + 2) * 64);
    __builtin_amdgcn_sched_barrier(0);

    // ---- P frags (per-wave buffer) + PV ----
    bf16x8 pf[2][2];
#pragma unroll
    for (int mi = 0; mi < 2; ++mi)
#pragma unroll
      for (int ks2 = 0; ks2 < 2; ++ks2)
        pf[mi][ks2] = *reinterpret_cast<const bf16x8*>(&Pw[(mi * 16 + lr) * 72 + ks2 * 32 + lg * 8]);
    __builtin_amdgcn_s_setprio(1);
#pragma unroll
    for (int ks2 = 0; ks2 < 2; ++ks2)
#pragma unroll
      for (int hf = 0; hf < 4; ++hf)
#pragma unroll
        for (int mi = 0; mi < 2; ++mi)
          o[mi][hf] = __builtin_amdgcn_mfma_f32_16x16x32_bf16(pf[mi][ks2], vf[ks2][hf], o[mi][hf], 0, 0, 0);
    __builtin_amdgcn_s_setprio(0);
  }

  // ---- deferred row-sum reduce + normalize + store ----
#pragma unroll
  for (int mi = 0; mi < 2; ++mi)
#pragma unroll
    for (int r = 0; r < 4; ++r) {
      float s = lsum[mi][r];
#pragma unroll
      for (int d = 1; d < 16; d <<= 1) s += __shfl_xor(s, d, 64);
      const float inv = 1.0f / s;
      const int srow = q0 + mi * 16 + lg * 4 + r;
#pragma unroll
      for (int hf = 0; hf < 4; ++hf) {
        const int h = hf * 16 + lr;
        AO[(size_t)(b * SEQ + srow) * D_MODEL + n * 64 + h] = f2bf(o[mi][hf][r] * inv);
      }
    }
}

// ---------------- launch ----------------
extern "C" void kernel_launch(void* const* d_in, const int* in_sizes, int n_in,
                              void* d_out, int out_size, void* d_ws, size_t ws_size,
                              hipStream_t stream) {
  const float* qw = (const float*)d_in[0];
  const float* kw = (const float*)d_in[1];
  const float* vw = (const float*)d_in[2];
  const float* ow = (const float*)d_in[3];
  const float* x  = (const float*)d_in[4];

  char* ws = (char*)d_ws;
  const size_t XB = (size_t)M_TOT * D_MODEL * 2;      // 8 MB
  const size_t WB = (size_t)D_MODEL * D_MODEL * 2;    // 2 MB
  unsigned short* Xb  = (unsigned short*)ws;  ws += XB;
  unsigned short* Wqb = (unsigned short*)ws;  ws += WB;  // Wq|Wk|Wv|Wo contiguous
  unsigned short* Wkb = (unsigned short*)ws;  ws += WB;
  unsigned short* Wvb = (unsigned short*)ws;  ws += WB;
  unsigned short* Wob = (unsigned short*)ws;  ws += WB;
  unsigned short* Qr  = (unsigned short*)ws;  ws += XB;
  unsigned short* Kr  = (unsigned short*)ws;  ws += XB;
  unsigned short* Vt  = (unsigned short*)ws;  ws += XB;
  unsigned short* AO  = (unsigned short*)ws;  ws += XB;
  float* ctab = (float*)ws;  ws += (size_t)SEQ * 32 * 4;
  float* stab = (float*)ws;  ws += (size_t)SEQ * 32 * 4;

  cvt_f32_bf16<<<(M_TOT * D_MODEL / 4) / 256, 256, 0, stream>>>(x, Xb, M_TOT * D_MODEL / 4);
  cvt_weights<<<(4 * D_MODEL * D_MODEL / 4) / 256, 256, 0, stream>>>(qw, kw, vw, ow, Wqb);
  rope_tables<<<(SEQ * 32) / 256, 256, 0, stream>>>(ctab, stab);

  // merged QKV projection: N = 3072
  gemm2<128, 128, 0><<<dim3(3072 / 128, M_TOT / 128), 256, 0, stream>>>(
      Xb, Wqb, Qr, Kr, Vt, nullptr, ctab, stab);

  attn_kernel<<<dim3(BATCH * 16, 16), 256, 0, stream>>>(Qr, Kr, Vt, AO);

  // final projection: N = 1024, 128x64 tile -> 512 blocks
  gemm2<128, 64, 2><<<dim3(D_MODEL / 64, M_TOT / 128), 256, 0, stream>>>(
      AO, Wob, nullptr, nullptr, nullptr, (float*)d_out, nullptr, nullptr);
}

// Round 11
// 115.479 us; speedup vs baseline: 2.0128x; 1.1055x over previous
//
#include <hip/hip_runtime.h>
#include <math.h>

typedef __attribute__((ext_vector_type(8))) short bf16x8;
typedef __attribute__((ext_vector_type(4))) float f32x4;

static constexpr int D_MODEL = 1024;
static constexpr int SEQ = 2048;
static constexpr int BATCH = 2;
static constexpr int M_TOT = BATCH * SEQ;   // 4096

__device__ __forceinline__ unsigned short f2bf(float f) {
  unsigned int u = __builtin_bit_cast(unsigned int, f);
  u += 0x7fffu + ((u >> 16) & 1u);   // round-to-nearest-even
  return (unsigned short)(u >> 16);
}

// async global -> LDS, 16B per lane.  LDS dst = wave-uniform base + lane*16.
// GLOBAL src is PER-LANE — caller must include the lane offset.
__device__ __forceinline__ void gld16(const unsigned short* g, unsigned short* l) {
  __builtin_amdgcn_global_load_lds(
      (const __attribute__((address_space(1))) unsigned int*)g,
      (__attribute__((address_space(3))) unsigned int*)l, 16, 0, 0);
}

// ---------------- prep: fp32 -> bf16 (vectorized) ----------------
__global__ void cvt_f32_bf16(const float* __restrict__ src,
                             unsigned short* __restrict__ dst, int n4) {
  int i = blockIdx.x * blockDim.x + threadIdx.x;
  if (i >= n4) return;
  const float4 v = reinterpret_cast<const float4*>(src)[i];
  ushort4 o;
  o.x = f2bf(v.x); o.y = f2bf(v.y); o.z = f2bf(v.z); o.w = f2bf(v.w);
  reinterpret_cast<ushort4*>(dst)[i] = o;
}

// all 4 weights in one dispatch; dst regions are contiguous (Wq|Wk|Wv|Wo).
__global__ void cvt_weights(const float* __restrict__ qw, const float* __restrict__ kw,
                            const float* __restrict__ vw, const float* __restrict__ ow,
                            unsigned short* __restrict__ dst) {
  int i = blockIdx.x * blockDim.x + threadIdx.x;   // over 4 * 2^18 float4 groups
  const int which = i >> 18;
  const int off = i & 262143;
  const float* src = (which == 0) ? qw : (which == 1) ? kw : (which == 2) ? vw : ow;
  const float4 v = reinterpret_cast<const float4*>(src)[off];
  ushort4 o;
  o.x = f2bf(v.x); o.y = f2bf(v.y); o.z = f2bf(v.z); o.w = f2bf(v.w);
  reinterpret_cast<ushort4*>(dst)[i] = o;
}

// ---------------- prep: interleaved RoPE table [SEQ][32] float2, bank-swizzled ----------------
// stored at p ^ (((s>>2)&1)<<3) so epilogue ds_read_b64 per lg-group hits distinct banks.
__global__ void rope_tables(float2* __restrict__ ct2) {
  int idx = blockIdx.x * blockDim.x + threadIdx.x;   // SEQ*32
  int s = idx >> 5;
  int p = idx & 31;
  float inv_freq = powf(10000.0f, -(float)p / 32.0f);
  float ang = (float)s * inv_freq;
  int psw = p ^ (((s >> 2) & 1) << 3);
  float2 cs; cs.x = cosf(ang); cs.y = sinf(ang);
  ct2[s * 32 + psw] = cs;
}

// ---------------- GEMM v3: counted-vmcnt k-loop + fast epilogue ----------------
// C[M][N] = A @ W^T.  BK=32, double-buffered, swizzled LDS (conflict-free).
// MODE 0 (QKV, N=3072): Q/K -> RoPE via LDS table -> [bn][s][64]; V -> LDS transpose
//   -> coalesced [bn][h][s].  MODE 2: fp32 row-major.
template <int BM, int BN, int MODE>
__global__ __launch_bounds__(256, 2)
void gemm2(const unsigned short* __restrict__ A,
           const unsigned short* __restrict__ W,
           unsigned short* __restrict__ Qd,
           unsigned short* __restrict__ Kd,
           unsigned short* __restrict__ Vd,
           float* __restrict__ Fd,
           const float2* __restrict__ ct2) {
  constexpr int MI = BM / 32, NI = BN / 32;
  constexpr int NKT = D_MODEL / 32;            // 32 k-steps
  constexpr int LOADS = BM / 64 + BN / 64;     // gld16 per wave per stage
  __shared__ __align__(16) unsigned short smem[2 * (BM + BN) * 32];  // 32KB @128x128
  unsigned short* Asm = smem;                  // [2][BM*32]
  unsigned short* Bsm = smem + 2 * BM * 32;    // [2][BN*32]
  const int tid  = threadIdx.x;
  const int lane = tid & 63;
  const int wave = tid >> 6;
  const int wm = wave >> 1, wn = wave & 1;
  const int m0 = blockIdx.y * BM;
  const int n0 = blockIdx.x * BN;
  const int lr = lane & 15, lg = lane >> 4;

  // staging: row = ch*16 + lane>>2, 16B chunk = lane&3, source pre-swizzled.
  const int srow = lane >> 2;
  const int scol = ((lane & 3) ^ ((lane >> 3) & 3)) * 8;

  auto stage = [&](int buf, int kt) {
    const int k0 = kt * 32;
#pragma unroll
    for (int rr = 0; rr < BM / 64; ++rr) {
      const int ch = rr * 4 + wave;
      gld16(&A[(size_t)(m0 + ch * 16 + srow) * D_MODEL + k0 + scol], &Asm[buf * BM * 32 + ch * 512]);
    }
#pragma unroll
    for (int rr = 0; rr < BN / 64; ++rr) {
      const int ch = rr * 4 + wave;
      gld16(&W[(size_t)(n0 + ch * 16 + srow) * D_MODEL + k0 + scol], &Bsm[buf * BN * 32 + ch * 512]);
    }
  };

  f32x4 acc[MI][NI] = {};

  stage(0, 0);
  stage(1, 1);
  __builtin_amdgcn_sched_barrier(0);

  const int swz = (lg ^ ((lr >> 1) & 3)) * 8;  // frag-read chunk swizzle

  for (int kt = 0; kt < NKT; ++kt) {
    const int cur = kt & 1;
    if (kt + 1 < NKT) {
      if constexpr (LOADS == 4) asm volatile("s_waitcnt vmcnt(4)" ::: "memory");
      else                      asm volatile("s_waitcnt vmcnt(3)" ::: "memory");
    } else {
      asm volatile("s_waitcnt vmcnt(0)" ::: "memory");
    }
    __builtin_amdgcn_s_barrier();
    __builtin_amdgcn_sched_barrier(0);

    bf16x8 af[MI], bfr[NI];
#pragma unroll
    for (int i = 0; i < MI; ++i)
      af[i] = *reinterpret_cast<const bf16x8*>(&Asm[cur * BM * 32 + (wm * (BM / 2) + i * 16 + lr) * 32 + swz]);
#pragma unroll
    for (int j = 0; j < NI; ++j)
      bfr[j] = *reinterpret_cast<const bf16x8*>(&Bsm[cur * BN * 32 + (wn * (BN / 2) + j * 16 + lr) * 32 + swz]);
    asm volatile("s_waitcnt lgkmcnt(0)" ::: "memory");
    __builtin_amdgcn_sched_barrier(0);
    __builtin_amdgcn_s_barrier();            // all waves done reading buf cur
    __builtin_amdgcn_sched_barrier(0);

    if (kt + 2 < NKT) stage(cur, kt + 2);
    __builtin_amdgcn_sched_barrier(0);

#pragma unroll
    for (int i = 0; i < MI; ++i)
#pragma unroll
      for (int j = 0; j < NI; ++j)
        acc[i][j] = __builtin_amdgcn_mfma_f32_16x16x32_bf16(af[i], bfr[j], acc[i][j], 0, 0, 0);
  }
  // NOTE: the loop's final read-complete s_barrier has synced all waves; smem is dead.

  if constexpr (MODE == 2) {
    // plain fp32 epilogue (coalesced)
#pragma unroll
    for (int i = 0; i < MI; ++i)
#pragma unroll
      for (int j = 0; j < NI; ++j)
#pragma unroll
        for (int r = 0; r < 4; ++r) {
          const int gm = m0 + wm * (BM / 2) + i * 16 + lg * 4 + r;
          const int gc = n0 + wn * (BN / 2) + j * 16 + lr;
          Fd[(size_t)gm * D_MODEL + gc] = acc[i][j][r];
        }
  } else {
    const int t = n0 >> 10;                    // uniform per block (128 | 1024)
    const int b = m0 >> 11;
    const int s_base = m0 & 2047;
    if (t < 2) {
      // ---- Q/K: RoPE via LDS table ----
      unsigned short* dstQ = (t == 0) ? Qd : Kd;
      // copy 32KB table slice [128 s][32 p] float2 into smem (linear).
      // PER-LANE source offset: lane*8 ushorts = 16B per lane.
      const unsigned short* gsrc = (const unsigned short*)(ct2 + (size_t)s_base * 32);
#pragma unroll
      for (int it = 0; it < 8; ++it) {
        const int ch = wave * 8 + it;
        gld16(&gsrc[ch * 512 + lane * 8], &smem[ch * 512]);
      }
      asm volatile("s_waitcnt vmcnt(0)" ::: "memory");
      __builtin_amdgcn_sched_barrier(0);
      __builtin_amdgcn_s_barrier();
      const float2* tbl = (const float2*)smem;
      const int nbase = (n0 & 1023) >> 6;
#pragma unroll
      for (int i = 0; i < MI; ++i) {
#pragma unroll
        for (int j = 0; j < NI; ++j) {
#pragma unroll
          for (int r = 0; r < 4; ++r) {
            const int sl = wm * (BM / 2) + i * 16 + lg * 4 + r;   // s_local 0..127
            const int h  = j * 16 + lr;                            // 0..63
            const int psw = (h >> 1) ^ (((sl >> 2) & 1) << 3);
            const float2 cs = tbl[sl * 32 + psw];
            float x = acc[i][j][r];
            const float part = __shfl_xor(x, 1, 64);
            x = (h & 1) ? (part * cs.y + x * cs.x) : (x * cs.x - part * cs.y);
            const int n = nbase + wn;
            dstQ[(size_t)((b * 16 + n) * SEQ + s_base + sl) * 64 + h] = f2bf(x);
          }
        }
      }
    } else {
      // ---- V: transpose via LDS, coalesced [bn][h][s] stores ----
      unsigned short* tile = smem;             // [64 cols][136]
      const int row = tid >> 2;                // 0..63
      const int ck  = tid & 3;
      for (int pass = 0; pass < 2; ++pass) {
        __builtin_amdgcn_s_barrier();
        if (wn == pass) {
#pragma unroll
          for (int i = 0; i < MI; ++i)
#pragma unroll
            for (int j = 0; j < NI; ++j)
#pragma unroll
              for (int r = 0; r < 4; ++r)
                tile[(j * 16 + lr) * 136 + wm * 64 + i * 16 + lg * 4 + r] = f2bf(acc[i][j][r]);
        }
        asm volatile("s_waitcnt lgkmcnt(0)" ::: "memory");
        __builtin_amdgcn_sched_barrier(0);
        __builtin_amdgcn_s_barrier();
        const int c = (n0 & 1023) + pass * 64 + row;
        const int n = c >> 6, h = c & 63;
        unsigned short* vrow = &Vd[(size_t)((b * 16 + n) * 64 + h) * SEQ + s_base + ck * 32];
        const unsigned short* lrow = &tile[row * 136 + ck * 32];
#pragma unroll
        for (int k = 0; k < 4; ++k)
          *reinterpret_cast<bf16x8*>(&vrow[k * 8]) = *reinterpret_cast<const bf16x8*>(&lrow[k * 8]);
      }
    }
  }
}

// ---------------- flash attention v8: counted-vmcnt pipeline + TLP (unchanged) ----------------
__global__ __launch_bounds__(256, 2)
void attn_kernel(const unsigned short* __restrict__ Q,
                 const unsigned short* __restrict__ K,
                 const unsigned short* __restrict__ Vt,
                 unsigned short* __restrict__ AO) {
  __shared__ __align__(16) unsigned short Ksh[2][4096];  // [buf][64 x 64] swizzled
  __shared__ __align__(16) unsigned short Vsh[2][4096];
  __shared__ unsigned short Pl[4][32 * 72];
  const int bn   = blockIdx.x;
  const int j    = (gridDim.y - 1) - blockIdx.y;   // heavy-first: j=15 dispatched first
  const int wave = threadIdx.x >> 6;
  const int lane = threadIdx.x & 63;
  const int lr = lane & 15, lg = lane >> 4;
  const int q0 = j * 128 + wave * 32;
  const unsigned short* Qh = Q  + (size_t)bn * SEQ * 64;
  const unsigned short* Kh = K  + (size_t)bn * SEQ * 64;
  const unsigned short* Vh = Vt + (size_t)bn * 64 * SEQ;
  unsigned short* Pw = &Pl[wave][0];
  const int b = bn >> 4, n = bn & 15;

  const int srow8 = lane >> 3;                 // row within 8-row chunk
  const int scolb = ((lane & 7) ^ srow8) * 8;  // inverse-swizzled source col (elements)

  auto stage = [&](int buf, int k0) {
#pragma unroll
    for (int c = 0; c < 2; ++c) {
      const int ch = wave * 2 + c;             // 8 chunks of 8 rows
      const int row = ch * 8 + srow8;
      gld16(&Kh[(size_t)(k0 + row) * 64 + scolb], &Ksh[buf][ch * 512]);
      gld16(&Vh[(size_t)row * SEQ + k0 + scolb], &Vsh[buf][ch * 512]);
    }
  };

  constexpr float KL2E = 0.125f * 1.44269504088896f;
  const int nt = 2 * j + 2;                    // causal k-tiles of 64

  bf16x8 qf[2][2];
#pragma unroll
  for (int mi = 0; mi < 2; ++mi)
#pragma unroll
    for (int ks = 0; ks < 2; ++ks)
      qf[mi][ks] = *reinterpret_cast<const bf16x8*>(
          &Qh[(size_t)(q0 + mi * 16 + lr) * 64 + ks * 32 + lg * 8]);
  asm volatile("s_waitcnt vmcnt(0)" ::: "memory");  // clean slate for counted waits
  __builtin_amdgcn_sched_barrier(0);

  f32x4 o[2][4] = {};
  float lsum[2][4] = {};

  stage(0, 0);
  stage(1, 64);
  __builtin_amdgcn_sched_barrier(0);

  for (int t = 0; t < nt; ++t) {
    const int cur = t & 1;
    const int k0 = t * 64;
    if (t + 1 < nt) { asm volatile("s_waitcnt vmcnt(4)" ::: "memory"); }
    else            { asm volatile("s_waitcnt vmcnt(0)" ::: "memory"); }
    __builtin_amdgcn_s_barrier();            // all waves' stage(t) visible
    __builtin_amdgcn_sched_barrier(0);

    const unsigned short* Kc = &Ksh[cur][0];
    const unsigned short* Vc = &Vsh[cur][0];

    bf16x8 kf[4][2];
#pragma unroll
    for (int nj = 0; nj < 4; ++nj)
#pragma unroll
      for (int ks = 0; ks < 2; ++ks) {
        const int R = nj * 16 + lr;
        const int p = (ks * 4 + lg) ^ (R & 7);
        kf[nj][ks] = *reinterpret_cast<const bf16x8*>(&Kc[R * 64 + p * 8]);
      }
    f32x4 sf[2][4] = {};
    __builtin_amdgcn_s_setprio(1);
#pragma unroll
    for (int nj = 0; nj < 4; ++nj)
#pragma unroll
      for (int ks = 0; ks < 2; ++ks)
#pragma unroll
        for (int mi = 0; mi < 2; ++mi)
          sf[mi][nj] = __builtin_amdgcn_mfma_f32_16x16x32_bf16(qf[mi][ks], kf[nj][ks], sf[mi][nj], 0, 0, 0);
    __builtin_amdgcn_s_setprio(0);

    if (k0 + 63 <= q0) {
#pragma unroll
      for (int mi = 0; mi < 2; ++mi)
#pragma unroll
        for (int nj = 0; nj < 4; ++nj)
#pragma unroll
          for (int r = 0; r < 4; ++r) {
            const float p = __builtin_amdgcn_exp2f(sf[mi][nj][r] * KL2E);
            lsum[mi][r] += p;
            Pw[(mi * 16 + lg * 4 + r) * 72 + nj * 16 + lr] = f2bf(p);
          }
    } else {
#pragma unroll
      for (int mi = 0; mi < 2; ++mi)
#pragma unroll
        for (int nj = 0; nj < 4; ++nj)
#pragma unroll
          for (int r = 0; r < 4; ++r) {
            const int qrow = q0 + mi * 16 + lg * 4 + r;
            const int kcol = k0 + nj * 16 + lr;
            const float p = (kcol <= qrow) ? __builtin_amdgcn_exp2f(sf[mi][nj][r] * KL2E) : 0.0f;
            lsum[mi][r] += p;
            Pw[(mi * 16 + lg * 4 + r) * 72 + nj * 16 + lr] = f2bf(p);
          }
    }

    bf16x8 vf[2][4];
#pragma unroll
    for (int ks2 = 0; ks2 < 2; ++ks2)
#pragma unroll
      for (int hf = 0; hf < 4; ++hf) {
        const int R = hf * 16 + lr;
        const int p = (ks2 * 4 + lg) ^ (R & 7);
        vf[ks2][hf] = *reinterpret_cast<const bf16x8*>(&Vc[R * 64 + p * 8]);
      }
    asm volatile("s_waitcnt lgkmcnt(0)" ::: "memory");
    __builtin_amdgcn_sched_barrier(0);
    __builtin_amdgcn_s_barrier();            // all waves done reading buf cur
    __builtin_amdgcn_sched_barrier(0);

    if (t + 2 < nt) stage(cur, (t + 2) * 64);
    __builtin_amdgcn_sched_barrier(0);

    bf16x8 pf[2][2];
#pragma unroll
    for (int mi = 0; mi < 2; ++mi)
#pragma unroll
      for (int ks2 = 0; ks2 < 2; ++ks2)
        pf[mi][ks2] = *reinterpret_cast<const bf16x8*>(&Pw[(mi * 16 + lr) * 72 + ks2 * 32 + lg * 8]);
    __builtin_amdgcn_s_setprio(1);
#pragma unroll
    for (int ks2 = 0; ks2 < 2; ++ks2)
#pragma unroll
      for (int hf = 0; hf < 4; ++hf)
#pragma unroll
        for (int mi = 0; mi < 2; ++mi)
          o[mi][hf] = __builtin_amdgcn_mfma_f32_16x16x32_bf16(pf[mi][ks2], vf[ks2][hf], o[mi][hf], 0, 0, 0);
    __builtin_amdgcn_s_setprio(0);
  }

#pragma unroll
  for (int mi = 0; mi < 2; ++mi)
#pragma unroll
    for (int r = 0; r < 4; ++r) {
      float s = lsum[mi][r];
#pragma unroll
      for (int d = 1; d < 16; d <<= 1) s += __shfl_xor(s, d, 64);
      const float inv = 1.0f / s;
      const int srow = q0 + mi * 16 + lg * 4 + r;
#pragma unroll
      for (int hf = 0; hf < 4; ++hf) {
        const int h = hf * 16 + lr;
        AO[(size_t)(b * SEQ + srow) * D_MODEL + n * 64 + h] = f2bf(o[mi][hf][r] * inv);
      }
    }
}

// ---------------- launch ----------------
extern "C" void kernel_launch(void* const* d_in, const int* in_sizes, int n_in,
                              void* d_out, int out_size, void* d_ws, size_t ws_size,
                              hipStream_t stream) {
  const float* qw = (const float*)d_in[0];
  const float* kw = (const float*)d_in[1];
  const float* vw = (const float*)d_in[2];
  const float* ow = (const float*)d_in[3];
  const float* x  = (const float*)d_in[4];

  char* ws = (char*)d_ws;
  const size_t XB = (size_t)M_TOT * D_MODEL * 2;      // 8 MB
  const size_t WB = (size_t)D_MODEL * D_MODEL * 2;    // 2 MB
  unsigned short* Xb  = (unsigned short*)ws;  ws += XB;
  unsigned short* Wqb = (unsigned short*)ws;  ws += WB;  // Wq|Wk|Wv|Wo contiguous
  unsigned short* Wkb = (unsigned short*)ws;  ws += WB;
  unsigned short* Wvb = (unsigned short*)ws;  ws += WB;
  unsigned short* Wob = (unsigned short*)ws;  ws += WB;
  unsigned short* Qr  = (unsigned short*)ws;  ws += XB;
  unsigned short* Kr  = (unsigned short*)ws;  ws += XB;
  unsigned short* Vt  = (unsigned short*)ws;  ws += XB;
  unsigned short* AO  = (unsigned short*)ws;  ws += XB;
  float2* ct2 = (float2*)ws;  ws += (size_t)SEQ * 32 * 8;   // interleaved rope table
  (void)Wkb; (void)Wvb;

  cvt_f32_bf16<<<(M_TOT * D_MODEL / 4) / 256, 256, 0, stream>>>(x, Xb, M_TOT * D_MODEL / 4);
  cvt_weights<<<(4 * D_MODEL * D_MODEL / 4) / 256, 256, 0, stream>>>(qw, kw, vw, ow, Wqb);
  rope_tables<<<(SEQ * 32) / 256, 256, 0, stream>>>(ct2);

  // merged QKV projection: N = 3072
  gemm2<128, 128, 0><<<dim3(3072 / 128, M_TOT / 128), 256, 0, stream>>>(
      Xb, Wqb, Qr, Kr, Vt, nullptr, ct2);

  attn_kernel<<<dim3(BATCH * 16, 16), 256, 0, stream>>>(Qr, Kr, Vt, AO);

  // final projection: N = 1024, 128x64 tile -> 512 blocks
  gemm2<128, 64, 2><<<dim3(D_MODEL / 64, M_TOT / 128), 256, 0, stream>>>(
      AO, Wob, nullptr, nullptr, nullptr, (float*)d_out, nullptr);
}

// Round 12
// 105.610 us; speedup vs baseline: 2.2009x; 1.0934x over previous
//
#include <hip/hip_runtime.h>
#include <math.h>

typedef __attribute__((ext_vector_type(8))) short bf16x8;
typedef __attribute__((ext_vector_type(4))) float f32x4;
typedef __attribute__((ext_vector_type(2))) unsigned int u32x2;

static constexpr int D_MODEL = 1024;
static constexpr int SEQ = 2048;
static constexpr int BATCH = 2;
static constexpr int M_TOT = BATCH * SEQ;   // 4096

__device__ __forceinline__ unsigned short f2bf(float f) {
  unsigned int u = __builtin_bit_cast(unsigned int, f);
  u += 0x7fffu + ((u >> 16) & 1u);   // round-to-nearest-even
  return (unsigned short)(u >> 16);
}

// pack 2 fp32 -> 2 bf16 in one instr (no builtin on gfx950; RNE)
__device__ __forceinline__ unsigned int cvtpk(float lo, float hi) {
  unsigned int r;
  asm volatile("v_cvt_pk_bf16_f32 %0, %1, %2" : "=v"(r) : "v"(lo), "v"(hi));
  return r;
}

// async global -> LDS, 16B per lane.  LDS dst = wave-uniform base + lane*16.
// GLOBAL src is PER-LANE — caller must include the lane offset.
__device__ __forceinline__ void gld16(const unsigned short* g, unsigned short* l) {
  __builtin_amdgcn_global_load_lds(
      (const __attribute__((address_space(1))) unsigned int*)g,
      (__attribute__((address_space(3))) unsigned int*)l, 16, 0, 0);
}

// ---------------- prep: fp32 -> bf16 (vectorized) ----------------
__global__ void cvt_f32_bf16(const float* __restrict__ src,
                             unsigned short* __restrict__ dst, int n4) {
  int i = blockIdx.x * blockDim.x + threadIdx.x;
  if (i >= n4) return;
  const float4 v = reinterpret_cast<const float4*>(src)[i];
  ushort4 o;
  o.x = f2bf(v.x); o.y = f2bf(v.y); o.z = f2bf(v.z); o.w = f2bf(v.w);
  reinterpret_cast<ushort4*>(dst)[i] = o;
}

// all 4 weights in one dispatch; dst regions are contiguous (Wq|Wk|Wv|Wo).
__global__ void cvt_weights(const float* __restrict__ qw, const float* __restrict__ kw,
                            const float* __restrict__ vw, const float* __restrict__ ow,
                            unsigned short* __restrict__ dst) {
  int i = blockIdx.x * blockDim.x + threadIdx.x;   // over 4 * 2^18 float4 groups
  const int which = i >> 18;
  const int off = i & 262143;
  const float* src = (which == 0) ? qw : (which == 1) ? kw : (which == 2) ? vw : ow;
  const float4 v = reinterpret_cast<const float4*>(src)[off];
  ushort4 o;
  o.x = f2bf(v.x); o.y = f2bf(v.y); o.z = f2bf(v.z); o.w = f2bf(v.w);
  reinterpret_cast<ushort4*>(dst)[i] = o;
}

// ---------------- prep: interleaved RoPE table [SEQ][32] float2, bank-swizzled ----------------
__global__ void rope_tables(float2* __restrict__ ct2) {
  int idx = blockIdx.x * blockDim.x + threadIdx.x;   // SEQ*32
  int s = idx >> 5;
  int p = idx & 31;
  float inv_freq = powf(10000.0f, -(float)p / 32.0f);
  float ang = (float)s * inv_freq;
  int psw = p ^ (((s >> 2) & 1) << 3);
  float2 cs; cs.x = cosf(ang); cs.y = sinf(ang);
  ct2[s * 32 + psw] = cs;
}

// ---------------- GEMM v3: counted-vmcnt k-loop + fast epilogue (unchanged) ----------------
template <int BM, int BN, int MODE>
__global__ __launch_bounds__(256, 2)
void gemm2(const unsigned short* __restrict__ A,
           const unsigned short* __restrict__ W,
           unsigned short* __restrict__ Qd,
           unsigned short* __restrict__ Kd,
           unsigned short* __restrict__ Vd,
           float* __restrict__ Fd,
           const float2* __restrict__ ct2) {
  constexpr int MI = BM / 32, NI = BN / 32;
  constexpr int NKT = D_MODEL / 32;            // 32 k-steps
  constexpr int LOADS = BM / 64 + BN / 64;     // gld16 per wave per stage
  __shared__ __align__(16) unsigned short smem[2 * (BM + BN) * 32];  // 32KB @128x128
  unsigned short* Asm = smem;                  // [2][BM*32]
  unsigned short* Bsm = smem + 2 * BM * 32;    // [2][BN*32]
  const int tid  = threadIdx.x;
  const int lane = tid & 63;
  const int wave = tid >> 6;
  const int wm = wave >> 1, wn = wave & 1;
  const int m0 = blockIdx.y * BM;
  const int n0 = blockIdx.x * BN;
  const int lr = lane & 15, lg = lane >> 4;

  const int srow = lane >> 2;
  const int scol = ((lane & 3) ^ ((lane >> 3) & 3)) * 8;

  auto stage = [&](int buf, int kt) {
    const int k0 = kt * 32;
#pragma unroll
    for (int rr = 0; rr < BM / 64; ++rr) {
      const int ch = rr * 4 + wave;
      gld16(&A[(size_t)(m0 + ch * 16 + srow) * D_MODEL + k0 + scol], &Asm[buf * BM * 32 + ch * 512]);
    }
#pragma unroll
    for (int rr = 0; rr < BN / 64; ++rr) {
      const int ch = rr * 4 + wave;
      gld16(&W[(size_t)(n0 + ch * 16 + srow) * D_MODEL + k0 + scol], &Bsm[buf * BN * 32 + ch * 512]);
    }
  };

  f32x4 acc[MI][NI] = {};

  stage(0, 0);
  stage(1, 1);
  __builtin_amdgcn_sched_barrier(0);

  const int swz = (lg ^ ((lr >> 1) & 3)) * 8;  // frag-read chunk swizzle

  for (int kt = 0; kt < NKT; ++kt) {
    const int cur = kt & 1;
    if (kt + 1 < NKT) {
      if constexpr (LOADS == 4) asm volatile("s_waitcnt vmcnt(4)" ::: "memory");
      else                      asm volatile("s_waitcnt vmcnt(3)" ::: "memory");
    } else {
      asm volatile("s_waitcnt vmcnt(0)" ::: "memory");
    }
    __builtin_amdgcn_s_barrier();
    __builtin_amdgcn_sched_barrier(0);

    bf16x8 af[MI], bfr[NI];
#pragma unroll
    for (int i = 0; i < MI; ++i)
      af[i] = *reinterpret_cast<const bf16x8*>(&Asm[cur * BM * 32 + (wm * (BM / 2) + i * 16 + lr) * 32 + swz]);
#pragma unroll
    for (int j = 0; j < NI; ++j)
      bfr[j] = *reinterpret_cast<const bf16x8*>(&Bsm[cur * BN * 32 + (wn * (BN / 2) + j * 16 + lr) * 32 + swz]);
    asm volatile("s_waitcnt lgkmcnt(0)" ::: "memory");
    __builtin_amdgcn_sched_barrier(0);
    __builtin_amdgcn_s_barrier();            // all waves done reading buf cur
    __builtin_amdgcn_sched_barrier(0);

    if (kt + 2 < NKT) stage(cur, kt + 2);
    __builtin_amdgcn_sched_barrier(0);

#pragma unroll
    for (int i = 0; i < MI; ++i)
#pragma unroll
      for (int j = 0; j < NI; ++j)
        acc[i][j] = __builtin_amdgcn_mfma_f32_16x16x32_bf16(af[i], bfr[j], acc[i][j], 0, 0, 0);
  }
  // loop's final read-complete s_barrier has synced all waves; smem is dead.

  if constexpr (MODE == 2) {
#pragma unroll
    for (int i = 0; i < MI; ++i)
#pragma unroll
      for (int j = 0; j < NI; ++j)
#pragma unroll
        for (int r = 0; r < 4; ++r) {
          const int gm = m0 + wm * (BM / 2) + i * 16 + lg * 4 + r;
          const int gc = n0 + wn * (BN / 2) + j * 16 + lr;
          Fd[(size_t)gm * D_MODEL + gc] = acc[i][j][r];
        }
  } else {
    const int t = n0 >> 10;                    // uniform per block
    const int b = m0 >> 11;
    const int s_base = m0 & 2047;
    if (t < 2) {
      // ---- Q/K: RoPE via LDS table ----
      unsigned short* dstQ = (t == 0) ? Qd : Kd;
      const unsigned short* gsrc = (const unsigned short*)(ct2 + (size_t)s_base * 32);
#pragma unroll
      for (int it = 0; it < 8; ++it) {
        const int ch = wave * 8 + it;
        gld16(&gsrc[ch * 512 + lane * 8], &smem[ch * 512]);
      }
      asm volatile("s_waitcnt vmcnt(0)" ::: "memory");
      __builtin_amdgcn_sched_barrier(0);
      __builtin_amdgcn_s_barrier();
      const float2* tbl = (const float2*)smem;
      const int nbase = (n0 & 1023) >> 6;
#pragma unroll
      for (int i = 0; i < MI; ++i) {
#pragma unroll
        for (int j = 0; j < NI; ++j) {
#pragma unroll
          for (int r = 0; r < 4; ++r) {
            const int sl = wm * (BM / 2) + i * 16 + lg * 4 + r;   // s_local 0..127
            const int h  = j * 16 + lr;                            // 0..63
            const int psw = (h >> 1) ^ (((sl >> 2) & 1) << 3);
            const float2 cs = tbl[sl * 32 + psw];
            float x = acc[i][j][r];
            const float part = __shfl_xor(x, 1, 64);
            x = (h & 1) ? (part * cs.y + x * cs.x) : (x * cs.x - part * cs.y);
            const int n = nbase + wn;
            dstQ[(size_t)((b * 16 + n) * SEQ + s_base + sl) * 64 + h] = f2bf(x);
          }
        }
      }
    } else {
      // ---- V: transpose via LDS, coalesced [bn][h][s] stores ----
      unsigned short* tile = smem;             // [64 cols][136]
      const int row = tid >> 2;                // 0..63
      const int ck  = tid & 3;
      for (int pass = 0; pass < 2; ++pass) {
        __builtin_amdgcn_s_barrier();
        if (wn == pass) {
#pragma unroll
          for (int i = 0; i < MI; ++i)
#pragma unroll
            for (int j = 0; j < NI; ++j)
#pragma unroll
              for (int r = 0; r < 4; ++r)
                tile[(j * 16 + lr) * 136 + wm * 64 + i * 16 + lg * 4 + r] = f2bf(acc[i][j][r]);
        }
        asm volatile("s_waitcnt lgkmcnt(0)" ::: "memory");
        __builtin_amdgcn_sched_barrier(0);
        __builtin_amdgcn_s_barrier();
        const int c = (n0 & 1023) + pass * 64 + row;
        const int n = c >> 6, h = c & 63;
        unsigned short* vrow = &Vd[(size_t)((b * 16 + n) * 64 + h) * SEQ + s_base + ck * 32];
        const unsigned short* lrow = &tile[row * 136 + ck * 32];
#pragma unroll
        for (int k = 0; k < 4; ++k)
          *reinterpret_cast<bf16x8*>(&vrow[k * 8]) = *reinterpret_cast<const bf16x8*>(&lrow[k * 8]);
      }
    }
  }
}

// ---------------- flash attention v9: swapped QK^T + packed P writes ----------------
// mfma(K,Q) puts 4 consecutive k per lane for one q-row (q = lr):
//   exp -> v_cvt_pk_bf16_f32 pairs -> 8 ds_write_b64 (was 32 ds_write_u16 + 4-op f2bf).
//   lsum becomes one scalar per mi (in-lane k sum); 2-shuffle final reduce.
// V-frag reads issued before the exp phase (latency hidden under exp VALU).
// Pipeline skeleton (counted vmcnt(4), raw barriers, swizzled block-shared K/V): unchanged.
__global__ __launch_bounds__(256, 2)
void attn_kernel(const unsigned short* __restrict__ Q,
                 const unsigned short* __restrict__ K,
                 const unsigned short* __restrict__ Vt,
                 unsigned short* __restrict__ AO) {
  __shared__ __align__(16) unsigned short Ksh[2][4096];  // [buf][64 x 64] swizzled
  __shared__ __align__(16) unsigned short Vsh[2][4096];
  __shared__ __align__(16) unsigned short Pl[4][32 * 72];
  const int bn   = blockIdx.x;
  const int j    = (gridDim.y - 1) - blockIdx.y;   // heavy-first
  const int wave = threadIdx.x >> 6;
  const int lane = threadIdx.x & 63;
  const int lr = lane & 15, lg = lane >> 4;
  const int q0 = j * 128 + wave * 32;
  const unsigned short* Qh = Q  + (size_t)bn * SEQ * 64;
  const unsigned short* Kh = K  + (size_t)bn * SEQ * 64;
  const unsigned short* Vh = Vt + (size_t)bn * 64 * SEQ;
  unsigned short* Pw = &Pl[wave][0];
  const int b = bn >> 4, n = bn & 15;

  const int srow8 = lane >> 3;
  const int scolb = ((lane & 7) ^ srow8) * 8;

  auto stage = [&](int buf, int k0) {
#pragma unroll
    for (int c = 0; c < 2; ++c) {
      const int ch = wave * 2 + c;
      const int row = ch * 8 + srow8;
      gld16(&Kh[(size_t)(k0 + row) * 64 + scolb], &Ksh[buf][ch * 512]);
      gld16(&Vh[(size_t)row * SEQ + k0 + scolb], &Vsh[buf][ch * 512]);
    }
  };

  constexpr float KL2E = 0.125f * 1.44269504088896f;
  const int nt = 2 * j + 2;

  bf16x8 qf[2][2];
#pragma unroll
  for (int mi = 0; mi < 2; ++mi)
#pragma unroll
    for (int ks = 0; ks < 2; ++ks)
      qf[mi][ks] = *reinterpret_cast<const bf16x8*>(
          &Qh[(size_t)(q0 + mi * 16 + lr) * 64 + ks * 32 + lg * 8]);
  asm volatile("s_waitcnt vmcnt(0)" ::: "memory");
  __builtin_amdgcn_sched_barrier(0);

  f32x4 o[2][4] = {};
  float ls[2] = {0.f, 0.f};                    // row-sum for q = mi*16+lr (in-lane k)

  stage(0, 0);
  stage(1, 64);
  __builtin_amdgcn_sched_barrier(0);

  for (int t = 0; t < nt; ++t) {
    const int cur = t & 1;
    const int k0 = t * 64;
    if (t + 1 < nt) { asm volatile("s_waitcnt vmcnt(4)" ::: "memory"); }
    else            { asm volatile("s_waitcnt vmcnt(0)" ::: "memory"); }
    __builtin_amdgcn_s_barrier();
    __builtin_amdgcn_sched_barrier(0);

    const unsigned short* Kc = &Ksh[cur][0];
    const unsigned short* Vc = &Vsh[cur][0];

    // ---- K frags (XOR-swizzled read) + swapped QK^T: sf = S^T tiles ----
    bf16x8 kf[4][2];
#pragma unroll
    for (int nj = 0; nj < 4; ++nj)
#pragma unroll
      for (int ks = 0; ks < 2; ++ks) {
        const int R = nj * 16 + lr;
        const int p = (ks * 4 + lg) ^ (R & 7);
        kf[nj][ks] = *reinterpret_cast<const bf16x8*>(&Kc[R * 64 + p * 8]);
      }
    f32x4 sf[2][4] = {};   // sf[mi][nj][r] = S[q=q0+mi*16+lr][k=k0+nj*16+lg*4+r]
    __builtin_amdgcn_s_setprio(1);
#pragma unroll
    for (int nj = 0; nj < 4; ++nj)
#pragma unroll
      for (int ks = 0; ks < 2; ++ks)
#pragma unroll
        for (int mi = 0; mi < 2; ++mi)
          sf[mi][nj] = __builtin_amdgcn_mfma_f32_16x16x32_bf16(kf[nj][ks], qf[mi][ks], sf[mi][nj], 0, 0, 0);
    __builtin_amdgcn_s_setprio(0);

    // ---- V frags issued now; latency hides under the exp phase ----
    bf16x8 vf[2][4];
#pragma unroll
    for (int ks2 = 0; ks2 < 2; ++ks2)
#pragma unroll
      for (int hf = 0; hf < 4; ++hf) {
        const int R = hf * 16 + lr;
        const int p = (ks2 * 4 + lg) ^ (R & 7);
        vf[ks2][hf] = *reinterpret_cast<const bf16x8*>(&Vc[R * 64 + p * 8]);
      }

    // ---- exp + pack(bf16x2) + 8x ds_write_b64 ----
    if (k0 + 63 <= q0) {                       // fully unmasked (wave-uniform)
#pragma unroll
      for (int mi = 0; mi < 2; ++mi)
#pragma unroll
        for (int nj = 0; nj < 4; ++nj) {
          const float p0 = __builtin_amdgcn_exp2f(sf[mi][nj][0] * KL2E);
          const float p1 = __builtin_amdgcn_exp2f(sf[mi][nj][1] * KL2E);
          const float p2 = __builtin_amdgcn_exp2f(sf[mi][nj][2] * KL2E);
          const float p3 = __builtin_amdgcn_exp2f(sf[mi][nj][3] * KL2E);
          ls[mi] += (p0 + p1) + (p2 + p3);
          u32x2 w; w[0] = cvtpk(p0, p1); w[1] = cvtpk(p2, p3);
          *reinterpret_cast<u32x2*>(&Pw[(mi * 16 + lr) * 72 + nj * 16 + lg * 4]) = w;
        }
    } else {
#pragma unroll
      for (int mi = 0; mi < 2; ++mi) {
        const int qrow = q0 + mi * 16 + lr;
#pragma unroll
        for (int nj = 0; nj < 4; ++nj) {
          const int kb = k0 + nj * 16 + lg * 4;
          float p[4];
#pragma unroll
          for (int r = 0; r < 4; ++r)
            p[r] = (kb + r <= qrow) ? __builtin_amdgcn_exp2f(sf[mi][nj][r] * KL2E) : 0.0f;
          ls[mi] += (p[0] + p[1]) + (p[2] + p[3]);
          u32x2 w; w[0] = cvtpk(p[0], p[1]); w[1] = cvtpk(p[2], p[3]);
          *reinterpret_cast<u32x2*>(&Pw[(mi * 16 + lr) * 72 + nj * 16 + lg * 4]) = w;
        }
      }
    }

    asm volatile("s_waitcnt lgkmcnt(0)" ::: "memory");   // V reads + P writes done
    __builtin_amdgcn_sched_barrier(0);
    __builtin_amdgcn_s_barrier();            // all waves done reading buf cur
    __builtin_amdgcn_sched_barrier(0);

    if (t + 2 < nt) stage(cur, (t + 2) * 64);
    __builtin_amdgcn_sched_barrier(0);

    // ---- P frags (normal [q][k] layout, unchanged) + PV ----
    bf16x8 pf[2][2];
#pragma unroll
    for (int mi = 0; mi < 2; ++mi)
#pragma unroll
      for (int ks2 = 0; ks2 < 2; ++ks2)
        pf[mi][ks2] = *reinterpret_cast<const bf16x8*>(&Pw[(mi * 16 + lr) * 72 + ks2 * 32 + lg * 8]);
    __builtin_amdgcn_s_setprio(1);
#pragma unroll
    for (int ks2 = 0; ks2 < 2; ++ks2)
#pragma unroll
      for (int hf = 0; hf < 4; ++hf)
#pragma unroll
        for (int mi = 0; mi < 2; ++mi)
          o[mi][hf] = __builtin_amdgcn_mfma_f32_16x16x32_bf16(pf[mi][ks2], vf[ks2][hf], o[mi][hf], 0, 0, 0);
    __builtin_amdgcn_s_setprio(0);
  }

  // ---- final reduce: lanes sharing lr hold partial sums for q=mi*16+lr ----
#pragma unroll
  for (int mi = 0; mi < 2; ++mi) {
    float s = ls[mi];
    s += __shfl_xor(s, 16, 64);
    s += __shfl_xor(s, 32, 64);
    ls[mi] = s;
  }
#pragma unroll
  for (int mi = 0; mi < 2; ++mi)
#pragma unroll
    for (int r = 0; r < 4; ++r) {
      const float sv = __shfl(ls[mi], lg * 4 + r, 64);   // lane lg*4+r holds q=mi*16+lg*4+r
      const float inv = 1.0f / sv;
      const int srow = q0 + mi * 16 + lg * 4 + r;
#pragma unroll
      for (int hf = 0; hf < 4; ++hf) {
        const int h = hf * 16 + lr;
        AO[(size_t)(b * SEQ + srow) * D_MODEL + n * 64 + h] = f2bf(o[mi][hf][r] * inv);
      }
    }
}

// ---------------- launch ----------------
extern "C" void kernel_launch(void* const* d_in, const int* in_sizes, int n_in,
                              void* d_out, int out_size, void* d_ws, size_t ws_size,
                              hipStream_t stream) {
  const float* qw = (const float*)d_in[0];
  const float* kw = (const float*)d_in[1];
  const float* vw = (const float*)d_in[2];
  const float* ow = (const float*)d_in[3];
  const float* x  = (const float*)d_in[4];

  char* ws = (char*)d_ws;
  const size_t XB = (size_t)M_TOT * D_MODEL * 2;      // 8 MB
  const size_t WB = (size_t)D_MODEL * D_MODEL * 2;    // 2 MB
  unsigned short* Xb  = (unsigned short*)ws;  ws += XB;
  unsigned short* Wqb = (unsigned short*)ws;  ws += WB;  // Wq|Wk|Wv|Wo contiguous
  unsigned short* Wkb = (unsigned short*)ws;  ws += WB;
  unsigned short* Wvb = (unsigned short*)ws;  ws += WB;
  unsigned short* Wob = (unsigned short*)ws;  ws += WB;
  unsigned short* Qr  = (unsigned short*)ws;  ws += XB;
  unsigned short* Kr  = (unsigned short*)ws;  ws += XB;
  unsigned short* Vt  = (unsigned short*)ws;  ws += XB;
  unsigned short* AO  = (unsigned short*)ws;  ws += XB;
  float2* ct2 = (float2*)ws;  ws += (size_t)SEQ * 32 * 8;   // interleaved rope table
  (void)Wkb; (void)Wvb;

  cvt_f32_bf16<<<(M_TOT * D_MODEL / 4) / 256, 256, 0, stream>>>(x, Xb, M_TOT * D_MODEL / 4);
  cvt_weights<<<(4 * D_MODEL * D_MODEL / 4) / 256, 256, 0, stream>>>(qw, kw, vw, ow, Wqb);
  rope_tables<<<(SEQ * 32) / 256, 256, 0, stream>>>(ct2);

  // merged QKV projection: N = 3072
  gemm2<128, 128, 0><<<dim3(3072 / 128, M_TOT / 128), 256, 0, stream>>>(
      Xb, Wqb, Qr, Kr, Vt, nullptr, ct2);

  attn_kernel<<<dim3(BATCH * 16, 16), 256, 0, stream>>>(Qr, Kr, Vt, AO);

  // final projection: N = 1024, 128x64 tile -> 512 blocks
  gemm2<128, 64, 2><<<dim3(D_MODEL / 64, M_TOT / 128), 256, 0, stream>>>(
      AO, Wob, nullptr, nullptr, nullptr, (float*)d_out, nullptr);
}